// Round 4
// baseline (4752.662 us; speedup 1.0000x reference)
//
#include <hip/hip_runtime.h>
#include <stdint.h>
#include <math.h>

// ============================================================================
// POGLM.sample — bit-exact replication of the JAX-CPU reference.
// R4: weight row held in 256 *named* scalar VGPRs (macro-expanded, asm-pinned;
//     arrays get demoted to scratch — R2/R3 lesson). Arithmetic identical to
//     the passing R1/R2/R3 kernels (absmax 0.0625).
// Variant knobs:
#define THREEFRY_PARTITIONABLE 1
#define BITS32_XOR 1
#define VSL_FMA 0
#define CONV_FMA 0
#define RAW_BARRIER 1    // 1 = lgkmcnt-only barrier (no store drain)
#define POISSON_BATCH 4  // ILP batch width
#define PIN_WEIGHTS 1    // 1 = asm-pin each named weight scalar
#define NT_STORES 1
// ============================================================================

#define T_BINS 1024
#define N_SAMP 64
#define N_NEUR 256
#define J_MAX 32

// --- strict (non-contractable) f32 ops ---
static __device__ __forceinline__ float fmul_s(float a, float b) {
#pragma clang fp contract(off)
  return a * b;
}
static __device__ __forceinline__ float fadd_s(float a, float b) {
#pragma clang fp contract(off)
  return a + b;
}
static __device__ __forceinline__ float fsub_s(float a, float b) {
#pragma clang fp contract(off)
  return a - b;
}

#if VSL_FMA
#define MULADD(a, b, c) __builtin_fmaf((a), (b), (c))
#else
#define MULADD(a, b, c) fadd_s(fmul_s((a), (b)), (c))
#endif

// --- Threefry-2x32, 20 rounds (exact JAX semantics) ---
static __device__ __forceinline__ uint32_t rotl(uint32_t v, uint32_t d) {
  return (v << d) | (v >> (32u - d));
}
static __device__ __forceinline__ void threefry2x32(uint32_t k0, uint32_t k1,
                                                    uint32_t x0, uint32_t x1,
                                                    uint32_t& o0, uint32_t& o1) {
  const uint32_t k2 = k0 ^ k1 ^ 0x1BD11BDAu;
  x0 += k0; x1 += k1;
#define TF_RD(r) { x0 += x1; x1 = rotl(x1, r); x1 ^= x0; }
  TF_RD(13u) TF_RD(15u) TF_RD(26u) TF_RD(6u)
  x0 += k1; x1 += k2 + 1u;
  TF_RD(17u) TF_RD(29u) TF_RD(16u) TF_RD(24u)
  x0 += k2; x1 += k0 + 2u;
  TF_RD(13u) TF_RD(15u) TF_RD(26u) TF_RD(6u)
  x0 += k0; x1 += k1 + 3u;
  TF_RD(17u) TF_RD(29u) TF_RD(16u) TF_RD(24u)
  x0 += k1; x1 += k2 + 4u;
  TF_RD(13u) TF_RD(15u) TF_RD(26u) TF_RD(6u)
  x0 += k2; x1 += k0 + 5u;
#undef TF_RD
  o0 = x0; o1 = x1;
}

// --- XLA CPU Cephes expf (GenerateVF32Exp) ---
static __device__ __forceinline__ float xla_expf(float input) {
  float x = fminf(input, 88.3762626647950f);
  x = fmaxf(x, -88.3762626647949f);
  float fx = floorf(MULADD(x, 1.44269504088896341f, 0.5f));
  float tmp = fmul_s(0.693359375f, fx);
  float z = fmul_s(-2.12194440e-4f, fx);
  x = fsub_s(x, tmp);
  x = fsub_s(x, z);
  z = fmul_s(x, x);
  float y = MULADD(x, 1.9875691500e-4f, 1.3981999507e-3f);
  y = MULADD(y, x, 8.3334519073e-3f);
  y = MULADD(y, x, 4.1665795894e-2f);
  y = MULADD(y, x, 1.6666665459e-1f);
  y = MULADD(y, x, 5.0000001201e-1f);
  y = MULADD(y, z, x);
  y = fadd_s(1.0f, y);
  int n = (int)fx;
  float p2n = __int_as_float((uint32_t)(n + 127) << 23);
  float res = fmul_s(y, p2n);
  return fmaxf(res, input);
}

// --- XLA CPU Cephes logf (GenerateVF32Log); u in {0} U [2^-23, 1) here ---
static __device__ __forceinline__ float xla_logf(float u) {
  if (u == 0.0f) return -INFINITY;
  uint32_t b = __float_as_uint(u);
  float e = (float)((int)(b >> 23) - 127) + 1.0f;
  float m = __uint_as_float((b & 0x007fffffu) | 0x3f000000u);
  if (m < 0.707106781186547524f) {
    e = fsub_s(e, 1.0f);
    m = fadd_s(m, m);
  }
  m = fsub_s(m, 1.0f);
  float z = fmul_s(m, m);
  float y = MULADD(m, 7.0376836292e-2f, -1.1514610310e-1f);
  y = MULADD(y, m, 1.1676998740e-1f);
  y = MULADD(y, m, -1.2420140846e-1f);
  y = MULADD(y, m, 1.4249322787e-1f);
  y = MULADD(y, m, -1.6668057665e-1f);
  y = MULADD(y, m, 2.0000714765e-1f);
  y = MULADD(y, m, -2.4999993993e-1f);
  y = MULADD(y, m, 3.3333331174e-1f);
  y = fmul_s(y, m);
  y = fmul_s(y, z);
  y = MULADD(e, -2.12194440e-4f, y);
  y = MULADD(z, -0.5f, y);
  m = fadd_s(m, y);
  m = MULADD(e, 0.693359375f, m);
  return m;
}

// ============================================================================
// Kernel 1: per-time-step subkey chains. sub layout: [t][j][2] u32.
// ============================================================================
__global__ void poglm_subkeys(uint32_t* __restrict__ sub) {
  int t = blockIdx.x * blockDim.x + threadIdx.x;
  if (t >= T_BINS) return;
  uint32_t kt0, kt1;
#if THREEFRY_PARTITIONABLE
  threefry2x32(0u, 1u, 0u, (uint32_t)t, kt0, kt1);
#else
  {
    uint32_t i0 = 2u * t, i1 = 2u * t + 1u, a0, a1, b0, b1;
    if (i0 < 1024u) { threefry2x32(0u, 1u, i0, i0 + 1024u, a0, a1); kt0 = a0; }
    else            { threefry2x32(0u, 1u, i0 - 1024u, i0, a0, a1); kt0 = a1; }
    if (i1 < 1024u) { threefry2x32(0u, 1u, i1, i1 + 1024u, b0, b1); kt1 = b0; }
    else            { threefry2x32(0u, 1u, i1 - 1024u, i1, b0, b1); kt1 = b1; }
  }
#endif
  uint32_t r0 = kt0, r1 = kt1;
  for (int j = 0; j < J_MAX; ++j) {
    uint32_t s0, s1, n0, n1;
#if THREEFRY_PARTITIONABLE
    threefry2x32(r0, r1, 0u, 1u, s0, s1);
    threefry2x32(r0, r1, 0u, 0u, n0, n1);
#else
    uint32_t p00, p01, p10, p11;
    threefry2x32(r0, r1, 0u, 2u, p00, p01);
    threefry2x32(r0, r1, 1u, 3u, p10, p11);
    n0 = p00; n1 = p10;
    s0 = p01; s1 = p11;
#endif
    sub[(size_t)t * (2 * J_MAX) + 2 * j + 0] = s0;
    sub[(size_t)t * (2 * J_MAX) + 2 * j + 1] = s1;
    r0 = n0; r1 = n1;
  }
}

// ---- macro machinery: 64 x float4 = 256 named scalar weights --------------
#define FOR64(M) \
  M(0) M(1) M(2) M(3) M(4) M(5) M(6) M(7) M(8) M(9) M(10) M(11) M(12) M(13) \
  M(14) M(15) M(16) M(17) M(18) M(19) M(20) M(21) M(22) M(23) M(24) M(25)   \
  M(26) M(27) M(28) M(29) M(30) M(31) M(32) M(33) M(34) M(35) M(36) M(37)   \
  M(38) M(39) M(40) M(41) M(42) M(43) M(44) M(45) M(46) M(47) M(48) M(49)   \
  M(50) M(51) M(52) M(53) M(54) M(55) M(56) M(57) M(58) M(59) M(60) M(61)   \
  M(62) M(63)

#define WDECL(i)                                                   \
  float wA##i, wB##i, wC##i, wD##i;                                \
  { const float4 v_ = w4[i];                                       \
    wA##i = v_.x; wB##i = v_.y; wC##i = v_.z; wD##i = v_.w; }

#if PIN_WEIGHTS
#define WPIN(i) asm volatile("" : "+v"(wA##i), "+v"(wB##i), "+v"(wC##i), "+v"(wD##i));
#else
#define WPIN(i)
#endif

// z-chain step: ascending k, fused FMA, conv read is wave-uniform (broadcast).
#define WFMA(i)                                                              \
  { const float4 cv_ = *reinterpret_cast<const float4*>(&conv_lds[buf][4 * (i)]); \
    zacc = __builtin_fmaf(cv_.x, wA##i, zacc);                               \
    zacc = __builtin_fmaf(cv_.y, wB##i, zacc);                               \
    zacc = __builtin_fmaf(cv_.z, wC##i, zacc);                               \
    zacc = __builtin_fmaf(cv_.w, wD##i, zacc); }

// ============================================================================
// Kernel 2: main simulation. Block = sample (64), thread = neuron (256).
// Whole weight row in named VGPRs. One raw barrier per step; conv_lds/sk_lds
// parity double-buffered (max skew 1 step => safe).
// ============================================================================
__global__ __launch_bounds__(256, 1)
void poglm_main(const float* __restrict__ basis, const float* __restrict__ weight,
                const float* __restrict__ bias, const uint32_t* __restrict__ sub,
                float* __restrict__ out) {
  const int s = blockIdx.x;
  const int n = threadIdx.x;

  __shared__ alignas(16) float conv_lds[2][N_NEUR];
  __shared__ uint32_t sk_lds[2][2 * J_MAX];
  __shared__ float fb_lds[20];  // fb[w] = basis[19-w]

  if (n < 20) fb_lds[n] = basis[19 - n];
  const float bias_n = bias[n];

  // Load this neuron's weight row into 256 named scalars and pin them.
  const float4* __restrict__ w4 = reinterpret_cast<const float4*>(weight + (size_t)n * N_NEUR);
  FOR64(WDECL)
  FOR64(WPIN)

  float hist[20];
#pragma unroll
  for (int i = 0; i < 20; ++i) hist[i] = 0.0f;

  const uint32_t idx = (uint32_t)(s * N_NEUR + n);
  const size_t plane = (size_t)N_SAMP * T_BINS * N_NEUR;
  float* __restrict__ out_spk = out + 0 * plane + (size_t)s * T_BINS * N_NEUR + n;
  float* __restrict__ out_cnv = out + 1 * plane + (size_t)s * T_BINS * N_NEUR + n;
  float* __restrict__ out_rte = out + 2 * plane + (size_t)s * T_BINS * N_NEUR + n;

  // Prefetch step-0 subkeys into a register (lanes 0..63 of wave 0).
  uint32_t skreg = 0;
  if (n < 2 * J_MAX) skreg = sub[n];

  __syncthreads();  // fb_lds visible (once; drain harmless here)

  for (int t = 0; t < T_BINS; ++t) {
    const int buf = t & 1;
    if (n < 2 * J_MAX) {
      sk_lds[buf][n] = skreg;
      const int tn = (t + 1 < T_BINS) ? t + 1 : t;
      skreg = sub[(size_t)tn * (2 * J_MAX) + n];
    }

    // conv: ascending w, unfused mul+add (order bit-locked)
    float conv = 0.0f;
#pragma unroll
    for (int w = 0; w < 20; ++w) {
#if CONV_FMA
      conv = __builtin_fmaf(fb_lds[w], hist[w], conv);
#else
      conv = fadd_s(conv, fmul_s(fb_lds[w], hist[w]));
#endif
    }
    conv_lds[buf][n] = conv;

#if RAW_BARRIER
    asm volatile("s_waitcnt lgkmcnt(0)\n\ts_barrier" ::: "memory");
#else
    __syncthreads();
#endif

    // z = sum_k conv[k]*W[n][k], fused FMA ascending k (order bit-locked), + bias
    float zacc = 0.0f;
    FOR64(WFMA)
    const float zb = fadd_s(zacc, bias_n);

    // lam = 1 / (1 + exp(-z))
    const float lam = 1.0f / fadd_s(1.0f, xla_expf(-zb));
    const float neg_lam = -lam;

    // Knuth Poisson, ILP-batched; values & comparison sequence unchanged.
    int r = 0;
    float S = 0.0f;
    bool done = false;
    for (int jb = 0; jb < J_MAX; jb += POISSON_BATCH) {
      float L[POISSON_BATCH];
#pragma unroll
      for (int q = 0; q < POISSON_BATCH; ++q) {
        const int j = jb + q;
        uint32_t o0, o1;
        threefry2x32(sk_lds[buf][2 * j], sk_lds[buf][2 * j + 1], 0u, idx, o0, o1);
#if BITS32_XOR
        const uint32_t bits = o0 ^ o1;
#else
        const uint32_t bits = o1;
#endif
        const float u = __uint_as_float((bits >> 9) | 0x3f800000u) - 1.0f;
        L[q] = xla_logf(u);
      }
#pragma unroll
      for (int q = 0; q < POISSON_BATCH; ++q) {
        if (!done) {
          S = fadd_s(S, L[q]);
          if (S > neg_lam) ++r; else done = true;
        }
      }
      if (__all(done)) break;
    }
    const float spk = (float)r;

#pragma unroll
    for (int i = 0; i < 19; ++i) hist[i] = hist[i + 1];
    hist[19] = spk;

    const size_t off = (size_t)t * N_NEUR;
#if NT_STORES
    __builtin_nontemporal_store(spk,  out_spk + off);
    __builtin_nontemporal_store(conv, out_cnv + off);
    __builtin_nontemporal_store(lam,  out_rte + off);
#else
    out_spk[off] = spk;
    out_cnv[off] = conv;
    out_rte[off] = lam;
#endif
#if !RAW_BARRIER
    __syncthreads();
#endif
  }
}

extern "C" void kernel_launch(void* const* d_in, const int* in_sizes, int n_in,
                              void* d_out, int out_size, void* d_ws, size_t ws_size,
                              hipStream_t stream) {
  const float* basis  = (const float*)d_in[0];
  const float* weight = (const float*)d_in[1];
  const float* bias   = (const float*)d_in[2];
  float* out = (float*)d_out;
  uint32_t* sub = (uint32_t*)d_ws;  // 1024 * 32 * 2 * 4 = 256 KiB

  hipLaunchKernelGGL(poglm_subkeys, dim3((T_BINS + 255) / 256), dim3(256), 0, stream, sub);
  hipLaunchKernelGGL(poglm_main, dim3(N_SAMP), dim3(256), 0, stream,
                     basis, weight, bias, sub, out);
}

// Round 5
// 4741.067 us; speedup vs baseline: 1.0024x; 1.0024x over previous
//
#include <hip/hip_runtime.h>
#include <stdint.h>
#include <math.h>

// ============================================================================
// POGLM.sample — bit-exact replication of the JAX-CPU reference.
// R5: weight row pinned in *AGPRs* (256-reg accumulator file, unused by this
//     kernel otherwise). R4 lesson: arch-VGPR class caps at 256/thread, so
//     "+v" pins of 256 weights + working set MUST spill; "+a" pins use the
//     other register file. Load->pin interleaved per float4 to keep init
//     pressure low. Arithmetic identical to passing R1-R4 (absmax 0.0625).
// Variant knobs:
#define THREEFRY_PARTITIONABLE 1
#define BITS32_XOR 1
#define VSL_FMA 0
#define CONV_FMA 0
#define RAW_BARRIER 1    // 1 = lgkmcnt-only barrier (no store drain)
#define POISSON_BATCH 4  // ILP batch width
#define WEIGHTS_IN_AGPR 1
#define NT_STORES 1
// ============================================================================

#define T_BINS 1024
#define N_SAMP 64
#define N_NEUR 256
#define J_MAX 32

// --- strict (non-contractable) f32 ops ---
static __device__ __forceinline__ float fmul_s(float a, float b) {
#pragma clang fp contract(off)
  return a * b;
}
static __device__ __forceinline__ float fadd_s(float a, float b) {
#pragma clang fp contract(off)
  return a + b;
}
static __device__ __forceinline__ float fsub_s(float a, float b) {
#pragma clang fp contract(off)
  return a - b;
}

#if VSL_FMA
#define MULADD(a, b, c) __builtin_fmaf((a), (b), (c))
#else
#define MULADD(a, b, c) fadd_s(fmul_s((a), (b)), (c))
#endif

// --- Threefry-2x32, 20 rounds (exact JAX semantics) ---
static __device__ __forceinline__ uint32_t rotl(uint32_t v, uint32_t d) {
  return (v << d) | (v >> (32u - d));
}
static __device__ __forceinline__ void threefry2x32(uint32_t k0, uint32_t k1,
                                                    uint32_t x0, uint32_t x1,
                                                    uint32_t& o0, uint32_t& o1) {
  const uint32_t k2 = k0 ^ k1 ^ 0x1BD11BDAu;
  x0 += k0; x1 += k1;
#define TF_RD(r) { x0 += x1; x1 = rotl(x1, r); x1 ^= x0; }
  TF_RD(13u) TF_RD(15u) TF_RD(26u) TF_RD(6u)
  x0 += k1; x1 += k2 + 1u;
  TF_RD(17u) TF_RD(29u) TF_RD(16u) TF_RD(24u)
  x0 += k2; x1 += k0 + 2u;
  TF_RD(13u) TF_RD(15u) TF_RD(26u) TF_RD(6u)
  x0 += k0; x1 += k1 + 3u;
  TF_RD(17u) TF_RD(29u) TF_RD(16u) TF_RD(24u)
  x0 += k1; x1 += k2 + 4u;
  TF_RD(13u) TF_RD(15u) TF_RD(26u) TF_RD(6u)
  x0 += k2; x1 += k0 + 5u;
#undef TF_RD
  o0 = x0; o1 = x1;
}

// --- XLA CPU Cephes expf (GenerateVF32Exp) ---
static __device__ __forceinline__ float xla_expf(float input) {
  float x = fminf(input, 88.3762626647950f);
  x = fmaxf(x, -88.3762626647949f);
  float fx = floorf(MULADD(x, 1.44269504088896341f, 0.5f));
  float tmp = fmul_s(0.693359375f, fx);
  float z = fmul_s(-2.12194440e-4f, fx);
  x = fsub_s(x, tmp);
  x = fsub_s(x, z);
  z = fmul_s(x, x);
  float y = MULADD(x, 1.9875691500e-4f, 1.3981999507e-3f);
  y = MULADD(y, x, 8.3334519073e-3f);
  y = MULADD(y, x, 4.1665795894e-2f);
  y = MULADD(y, x, 1.6666665459e-1f);
  y = MULADD(y, x, 5.0000001201e-1f);
  y = MULADD(y, z, x);
  y = fadd_s(1.0f, y);
  int n = (int)fx;
  float p2n = __int_as_float((uint32_t)(n + 127) << 23);
  float res = fmul_s(y, p2n);
  return fmaxf(res, input);
}

// --- XLA CPU Cephes logf (GenerateVF32Log); u in {0} U [2^-23, 1) here ---
static __device__ __forceinline__ float xla_logf(float u) {
  if (u == 0.0f) return -INFINITY;
  uint32_t b = __float_as_uint(u);
  float e = (float)((int)(b >> 23) - 127) + 1.0f;
  float m = __uint_as_float((b & 0x007fffffu) | 0x3f000000u);
  if (m < 0.707106781186547524f) {
    e = fsub_s(e, 1.0f);
    m = fadd_s(m, m);
  }
  m = fsub_s(m, 1.0f);
  float z = fmul_s(m, m);
  float y = MULADD(m, 7.0376836292e-2f, -1.1514610310e-1f);
  y = MULADD(y, m, 1.1676998740e-1f);
  y = MULADD(y, m, -1.2420140846e-1f);
  y = MULADD(y, m, 1.4249322787e-1f);
  y = MULADD(y, m, -1.6668057665e-1f);
  y = MULADD(y, m, 2.0000714765e-1f);
  y = MULADD(y, m, -2.4999993993e-1f);
  y = MULADD(y, m, 3.3333331174e-1f);
  y = fmul_s(y, m);
  y = fmul_s(y, z);
  y = MULADD(e, -2.12194440e-4f, y);
  y = MULADD(z, -0.5f, y);
  m = fadd_s(m, y);
  m = MULADD(e, 0.693359375f, m);
  return m;
}

// ============================================================================
// Kernel 1: per-time-step subkey chains. sub layout: [t][j][2] u32.
// ============================================================================
__global__ void poglm_subkeys(uint32_t* __restrict__ sub) {
  int t = blockIdx.x * blockDim.x + threadIdx.x;
  if (t >= T_BINS) return;
  uint32_t kt0, kt1;
#if THREEFRY_PARTITIONABLE
  threefry2x32(0u, 1u, 0u, (uint32_t)t, kt0, kt1);
#else
  {
    uint32_t i0 = 2u * t, i1 = 2u * t + 1u, a0, a1, b0, b1;
    if (i0 < 1024u) { threefry2x32(0u, 1u, i0, i0 + 1024u, a0, a1); kt0 = a0; }
    else            { threefry2x32(0u, 1u, i0 - 1024u, i0, a0, a1); kt0 = a1; }
    if (i1 < 1024u) { threefry2x32(0u, 1u, i1, i1 + 1024u, b0, b1); kt1 = b0; }
    else            { threefry2x32(0u, 1u, i1 - 1024u, i1, b0, b1); kt1 = b1; }
  }
#endif
  uint32_t r0 = kt0, r1 = kt1;
  for (int j = 0; j < J_MAX; ++j) {
    uint32_t s0, s1, n0, n1;
#if THREEFRY_PARTITIONABLE
    threefry2x32(r0, r1, 0u, 1u, s0, s1);
    threefry2x32(r0, r1, 0u, 0u, n0, n1);
#else
    uint32_t p00, p01, p10, p11;
    threefry2x32(r0, r1, 0u, 2u, p00, p01);
    threefry2x32(r0, r1, 1u, 3u, p10, p11);
    n0 = p00; n1 = p10;
    s0 = p01; s1 = p11;
#endif
    sub[(size_t)t * (2 * J_MAX) + 2 * j + 0] = s0;
    sub[(size_t)t * (2 * J_MAX) + 2 * j + 1] = s1;
    r0 = n0; r1 = n1;
  }
}

// ---- macro machinery: 64 x float4 = 256 named scalar weights --------------
#define FOR64(M) \
  M(0) M(1) M(2) M(3) M(4) M(5) M(6) M(7) M(8) M(9) M(10) M(11) M(12) M(13) \
  M(14) M(15) M(16) M(17) M(18) M(19) M(20) M(21) M(22) M(23) M(24) M(25)   \
  M(26) M(27) M(28) M(29) M(30) M(31) M(32) M(33) M(34) M(35) M(36) M(37)   \
  M(38) M(39) M(40) M(41) M(42) M(43) M(44) M(45) M(46) M(47) M(48) M(49)   \
  M(50) M(51) M(52) M(53) M(54) M(55) M(56) M(57) M(58) M(59) M(60) M(61)   \
  M(62) M(63)

#define WDECL(i) float wA##i, wB##i, wC##i, wD##i;

#if WEIGHTS_IN_AGPR
// Load one float4, then immediately pin the 4 scalars into AGPRs: init-time
// arch-VGPR pressure stays ~O(8); live ranges across the t-loop are AGPR-class
// (256 available, otherwise unused — no MFMA in this kernel).
#define WLOADPIN(i)                                                  \
  { const float4 v_ = w4[i];                                         \
    wA##i = v_.x; wB##i = v_.y; wC##i = v_.z; wD##i = v_.w;          \
    asm volatile("" : "+a"(wA##i), "+a"(wB##i), "+a"(wC##i), "+a"(wD##i)); }
#else
#define WLOADPIN(i)                                                  \
  { const float4 v_ = w4[i];                                         \
    wA##i = v_.x; wB##i = v_.y; wC##i = v_.z; wD##i = v_.w;          \
    asm volatile("" : "+v"(wA##i), "+v"(wB##i), "+v"(wC##i), "+v"(wD##i)); }
#endif

// z-chain step: ascending k, fused FMA; conv read is wave-uniform (broadcast).
#define WFMA(i)                                                              \
  { const float4 cv_ = *reinterpret_cast<const float4*>(&conv_lds[buf][4 * (i)]); \
    zacc = __builtin_fmaf(cv_.x, wA##i, zacc);                               \
    zacc = __builtin_fmaf(cv_.y, wB##i, zacc);                               \
    zacc = __builtin_fmaf(cv_.z, wC##i, zacc);                               \
    zacc = __builtin_fmaf(cv_.w, wD##i, zacc); }

// ============================================================================
// Kernel 2: main simulation. Block = sample (64), thread = neuron (256).
// Whole weight row resident in AGPRs. One raw barrier per step; conv_lds and
// sk_lds parity double-buffered (max skew 1 step => safe).
// ============================================================================
__global__ __launch_bounds__(256, 1)
void poglm_main(const float* __restrict__ basis, const float* __restrict__ weight,
                const float* __restrict__ bias, const uint32_t* __restrict__ sub,
                float* __restrict__ out) {
  const int s = blockIdx.x;
  const int n = threadIdx.x;

  __shared__ alignas(16) float conv_lds[2][N_NEUR];
  __shared__ uint32_t sk_lds[2][2 * J_MAX];
  __shared__ float fb_lds[20];  // fb[w] = basis[19-w]

  if (n < 20) fb_lds[n] = basis[19 - n];
  const float bias_n = bias[n];

  // Load this neuron's weight row into 256 named scalars pinned in AGPRs.
  const float4* __restrict__ w4 = reinterpret_cast<const float4*>(weight + (size_t)n * N_NEUR);
  FOR64(WDECL)
  FOR64(WLOADPIN)

  float hist[20];
#pragma unroll
  for (int i = 0; i < 20; ++i) hist[i] = 0.0f;

  const uint32_t idx = (uint32_t)(s * N_NEUR + n);
  const size_t plane = (size_t)N_SAMP * T_BINS * N_NEUR;
  float* __restrict__ out_spk = out + 0 * plane + (size_t)s * T_BINS * N_NEUR + n;
  float* __restrict__ out_cnv = out + 1 * plane + (size_t)s * T_BINS * N_NEUR + n;
  float* __restrict__ out_rte = out + 2 * plane + (size_t)s * T_BINS * N_NEUR + n;

  // Prefetch step-0 subkeys into a register (lanes 0..63 of wave 0).
  uint32_t skreg = 0;
  if (n < 2 * J_MAX) skreg = sub[n];

  __syncthreads();  // fb_lds visible (once; drain harmless here)

  for (int t = 0; t < T_BINS; ++t) {
    const int buf = t & 1;
    if (n < 2 * J_MAX) {
      sk_lds[buf][n] = skreg;
      const int tn = (t + 1 < T_BINS) ? t + 1 : t;
      skreg = sub[(size_t)tn * (2 * J_MAX) + n];
    }

    // conv: ascending w, unfused mul+add (order bit-locked)
    float conv = 0.0f;
#pragma unroll
    for (int w = 0; w < 20; ++w) {
#if CONV_FMA
      conv = __builtin_fmaf(fb_lds[w], hist[w], conv);
#else
      conv = fadd_s(conv, fmul_s(fb_lds[w], hist[w]));
#endif
    }
    conv_lds[buf][n] = conv;

#if RAW_BARRIER
    asm volatile("s_waitcnt lgkmcnt(0)\n\ts_barrier" ::: "memory");
#else
    __syncthreads();
#endif

    // z = sum_k conv[k]*W[n][k], fused FMA ascending k (order bit-locked), + bias
    float zacc = 0.0f;
    FOR64(WFMA)
    const float zb = fadd_s(zacc, bias_n);

    // lam = 1 / (1 + exp(-z))
    const float lam = 1.0f / fadd_s(1.0f, xla_expf(-zb));
    const float neg_lam = -lam;

    // Knuth Poisson, ILP-batched; values & comparison sequence unchanged.
    int r = 0;
    float S = 0.0f;
    bool done = false;
    for (int jb = 0; jb < J_MAX; jb += POISSON_BATCH) {
      float L[POISSON_BATCH];
#pragma unroll
      for (int q = 0; q < POISSON_BATCH; ++q) {
        const int j = jb + q;
        uint32_t o0, o1;
        threefry2x32(sk_lds[buf][2 * j], sk_lds[buf][2 * j + 1], 0u, idx, o0, o1);
#if BITS32_XOR
        const uint32_t bits = o0 ^ o1;
#else
        const uint32_t bits = o1;
#endif
        const float u = __uint_as_float((bits >> 9) | 0x3f800000u) - 1.0f;
        L[q] = xla_logf(u);
      }
#pragma unroll
      for (int q = 0; q < POISSON_BATCH; ++q) {
        if (!done) {
          S = fadd_s(S, L[q]);
          if (S > neg_lam) ++r; else done = true;
        }
      }
      if (__all(done)) break;
    }
    const float spk = (float)r;

#pragma unroll
    for (int i = 0; i < 19; ++i) hist[i] = hist[i + 1];
    hist[19] = spk;

    const size_t off = (size_t)t * N_NEUR;
#if NT_STORES
    __builtin_nontemporal_store(spk,  out_spk + off);
    __builtin_nontemporal_store(conv, out_cnv + off);
    __builtin_nontemporal_store(lam,  out_rte + off);
#else
    out_spk[off] = spk;
    out_cnv[off] = conv;
    out_rte[off] = lam;
#endif
#if !RAW_BARRIER
    __syncthreads();
#endif
  }
}

extern "C" void kernel_launch(void* const* d_in, const int* in_sizes, int n_in,
                              void* d_out, int out_size, void* d_ws, size_t ws_size,
                              hipStream_t stream) {
  const float* basis  = (const float*)d_in[0];
  const float* weight = (const float*)d_in[1];
  const float* bias   = (const float*)d_in[2];
  float* out = (float*)d_out;
  uint32_t* sub = (uint32_t*)d_ws;  // 1024 * 32 * 2 * 4 = 256 KiB

  hipLaunchKernelGGL(poglm_subkeys, dim3((T_BINS + 255) / 256), dim3(256), 0, stream, sub);
  hipLaunchKernelGGL(poglm_main, dim3(N_SAMP), dim3(256), 0, stream,
                     basis, weight, bias, sub, out);
}

// Round 6
// 3941.324 us; speedup vs baseline: 1.2059x; 1.2029x over previous
//
#include <hip/hip_runtime.h>
#include <stdint.h>
#include <math.h>

// ============================================================================
// POGLM.sample — bit-exact replication of the JAX-CPU reference.
// R6: weight matrix fully resident per block:
//       k in [0,128)   -> 128 named VGPR scalars per thread (fits under the
//                         256 arch-VGPR cap; R2-R5 failed because 256 didn't)
//       k in [128,256) -> 128 KB dynamic LDS, XOR-swizzled float4 slots
//                         (s ^ (n&31)) so same-column reads are 2-way (free).
//     Zero per-step weight traffic. Arithmetic identical to passing R1-R5.
// Variant knobs:
#define THREEFRY_PARTITIONABLE 1
#define BITS32_XOR 1
#define VSL_FMA 0
#define CONV_FMA 0
#define RAW_BARRIER 1
#define POISSON_BATCH 4
#define PIN_REG_HALF 1
#define NT_STORES 1
// ============================================================================

#define T_BINS 1024
#define N_SAMP 64
#define N_NEUR 256
#define J_MAX 32

// Dynamic LDS layout (bytes):
//   [0, 131072)            wlds: [256 rows][32 float4 slots], swizzled
//   [131072, 133120)       conv: 2 buffers x 256 floats
//   [133120, 133632)       sk:   2 buffers x 64 u32
//   [133632, 133712)       fb:   20 floats
#define WLDS_BYTES  (N_NEUR * 128 * 4)
#define CONV_OFF    WLDS_BYTES
#define SK_OFF      (CONV_OFF + 2 * N_NEUR * 4)
#define FB_OFF      (SK_OFF + 2 * 2 * J_MAX * 4)
#define LDS_BYTES   (FB_OFF + 20 * 4)

// --- strict (non-contractable) f32 ops ---
static __device__ __forceinline__ float fmul_s(float a, float b) {
#pragma clang fp contract(off)
  return a * b;
}
static __device__ __forceinline__ float fadd_s(float a, float b) {
#pragma clang fp contract(off)
  return a + b;
}
static __device__ __forceinline__ float fsub_s(float a, float b) {
#pragma clang fp contract(off)
  return a - b;
}

#if VSL_FMA
#define MULADD(a, b, c) __builtin_fmaf((a), (b), (c))
#else
#define MULADD(a, b, c) fadd_s(fmul_s((a), (b)), (c))
#endif

// --- Threefry-2x32, 20 rounds (exact JAX semantics) ---
static __device__ __forceinline__ uint32_t rotl(uint32_t v, uint32_t d) {
  return (v << d) | (v >> (32u - d));
}
static __device__ __forceinline__ void threefry2x32(uint32_t k0, uint32_t k1,
                                                    uint32_t x0, uint32_t x1,
                                                    uint32_t& o0, uint32_t& o1) {
  const uint32_t k2 = k0 ^ k1 ^ 0x1BD11BDAu;
  x0 += k0; x1 += k1;
#define TF_RD(r) { x0 += x1; x1 = rotl(x1, r); x1 ^= x0; }
  TF_RD(13u) TF_RD(15u) TF_RD(26u) TF_RD(6u)
  x0 += k1; x1 += k2 + 1u;
  TF_RD(17u) TF_RD(29u) TF_RD(16u) TF_RD(24u)
  x0 += k2; x1 += k0 + 2u;
  TF_RD(13u) TF_RD(15u) TF_RD(26u) TF_RD(6u)
  x0 += k0; x1 += k1 + 3u;
  TF_RD(17u) TF_RD(29u) TF_RD(16u) TF_RD(24u)
  x0 += k1; x1 += k2 + 4u;
  TF_RD(13u) TF_RD(15u) TF_RD(26u) TF_RD(6u)
  x0 += k2; x1 += k0 + 5u;
#undef TF_RD
  o0 = x0; o1 = x1;
}

// --- XLA CPU Cephes expf (GenerateVF32Exp) ---
static __device__ __forceinline__ float xla_expf(float input) {
  float x = fminf(input, 88.3762626647950f);
  x = fmaxf(x, -88.3762626647949f);
  float fx = floorf(MULADD(x, 1.44269504088896341f, 0.5f));
  float tmp = fmul_s(0.693359375f, fx);
  float z = fmul_s(-2.12194440e-4f, fx);
  x = fsub_s(x, tmp);
  x = fsub_s(x, z);
  z = fmul_s(x, x);
  float y = MULADD(x, 1.9875691500e-4f, 1.3981999507e-3f);
  y = MULADD(y, x, 8.3334519073e-3f);
  y = MULADD(y, x, 4.1665795894e-2f);
  y = MULADD(y, x, 1.6666665459e-1f);
  y = MULADD(y, x, 5.0000001201e-1f);
  y = MULADD(y, z, x);
  y = fadd_s(1.0f, y);
  int n = (int)fx;
  float p2n = __int_as_float((uint32_t)(n + 127) << 23);
  float res = fmul_s(y, p2n);
  return fmaxf(res, input);
}

// --- XLA CPU Cephes logf (GenerateVF32Log); u in {0} U [2^-23, 1) here ---
static __device__ __forceinline__ float xla_logf(float u) {
  if (u == 0.0f) return -INFINITY;
  uint32_t b = __float_as_uint(u);
  float e = (float)((int)(b >> 23) - 127) + 1.0f;
  float m = __uint_as_float((b & 0x007fffffu) | 0x3f000000u);
  if (m < 0.707106781186547524f) {
    e = fsub_s(e, 1.0f);
    m = fadd_s(m, m);
  }
  m = fsub_s(m, 1.0f);
  float z = fmul_s(m, m);
  float y = MULADD(m, 7.0376836292e-2f, -1.1514610310e-1f);
  y = MULADD(y, m, 1.1676998740e-1f);
  y = MULADD(y, m, -1.2420140846e-1f);
  y = MULADD(y, m, 1.4249322787e-1f);
  y = MULADD(y, m, -1.6668057665e-1f);
  y = MULADD(y, m, 2.0000714765e-1f);
  y = MULADD(y, m, -2.4999993993e-1f);
  y = MULADD(y, m, 3.3333331174e-1f);
  y = fmul_s(y, m);
  y = fmul_s(y, z);
  y = MULADD(e, -2.12194440e-4f, y);
  y = MULADD(z, -0.5f, y);
  m = fadd_s(m, y);
  m = MULADD(e, 0.693359375f, m);
  return m;
}

// ============================================================================
// Kernel 1: per-time-step subkey chains. sub layout: [t][j][2] u32.
// ============================================================================
__global__ void poglm_subkeys(uint32_t* __restrict__ sub) {
  int t = blockIdx.x * blockDim.x + threadIdx.x;
  if (t >= T_BINS) return;
  uint32_t kt0, kt1;
#if THREEFRY_PARTITIONABLE
  threefry2x32(0u, 1u, 0u, (uint32_t)t, kt0, kt1);
#else
  {
    uint32_t i0 = 2u * t, i1 = 2u * t + 1u, a0, a1, b0, b1;
    if (i0 < 1024u) { threefry2x32(0u, 1u, i0, i0 + 1024u, a0, a1); kt0 = a0; }
    else            { threefry2x32(0u, 1u, i0 - 1024u, i0, a0, a1); kt0 = a1; }
    if (i1 < 1024u) { threefry2x32(0u, 1u, i1, i1 + 1024u, b0, b1); kt1 = b0; }
    else            { threefry2x32(0u, 1u, i1 - 1024u, i1, b0, b1); kt1 = b1; }
  }
#endif
  uint32_t r0 = kt0, r1 = kt1;
  for (int j = 0; j < J_MAX; ++j) {
    uint32_t s0, s1, n0, n1;
#if THREEFRY_PARTITIONABLE
    threefry2x32(r0, r1, 0u, 1u, s0, s1);
    threefry2x32(r0, r1, 0u, 0u, n0, n1);
#else
    uint32_t p00, p01, p10, p11;
    threefry2x32(r0, r1, 0u, 2u, p00, p01);
    threefry2x32(r0, r1, 1u, 3u, p10, p11);
    n0 = p00; n1 = p10;
    s0 = p01; s1 = p11;
#endif
    sub[(size_t)t * (2 * J_MAX) + 2 * j + 0] = s0;
    sub[(size_t)t * (2 * J_MAX) + 2 * j + 1] = s1;
    r0 = n0; r1 = n1;
  }
}

// ---- macro machinery: 32 x float4 = 128 named scalar weights (k in [0,128))
#define FOR32(M) \
  M(0) M(1) M(2) M(3) M(4) M(5) M(6) M(7) M(8) M(9) M(10) M(11) M(12) M(13) \
  M(14) M(15) M(16) M(17) M(18) M(19) M(20) M(21) M(22) M(23) M(24) M(25)   \
  M(26) M(27) M(28) M(29) M(30) M(31)

#define WDECL(i) float wA##i, wB##i, wC##i, wD##i;

#if PIN_REG_HALF
#define WLOADPIN(i)                                                  \
  { const float4 v_ = w4[i];                                         \
    wA##i = v_.x; wB##i = v_.y; wC##i = v_.z; wD##i = v_.w;          \
    asm volatile("" : "+v"(wA##i), "+v"(wB##i), "+v"(wC##i), "+v"(wD##i)); }
#else
#define WLOADPIN(i)                                                  \
  { const float4 v_ = w4[i];                                         \
    wA##i = v_.x; wB##i = v_.y; wC##i = v_.z; wD##i = v_.w; }
#endif

// z-chain register-half step: ascending k, fused FMA; conv read wave-uniform.
#define WFMA(i)                                                      \
  { const float4 cv_ = convbuf4[i];                                  \
    zacc = __builtin_fmaf(cv_.x, wA##i, zacc);                       \
    zacc = __builtin_fmaf(cv_.y, wB##i, zacc);                       \
    zacc = __builtin_fmaf(cv_.z, wC##i, zacc);                       \
    zacc = __builtin_fmaf(cv_.w, wD##i, zacc); }

// ============================================================================
// Kernel 2: main simulation. Block = sample (64), thread = neuron (256).
// ============================================================================
__global__ __launch_bounds__(256, 1)
void poglm_main(const float* __restrict__ basis, const float* __restrict__ weight,
                const float* __restrict__ bias, const uint32_t* __restrict__ sub,
                float* __restrict__ out) {
  extern __shared__ char lds[];
  float4*   wlds4 = reinterpret_cast<float4*>(lds);                 // [256][32] swizzled
  float*    convb = reinterpret_cast<float*>(lds + CONV_OFF);       // [2][256]
  uint32_t* skb   = reinterpret_cast<uint32_t*>(lds + SK_OFF);      // [2][64]
  float*    fb    = reinterpret_cast<float*>(lds + FB_OFF);         // [20]

  const int s = blockIdx.x;
  const int n = threadIdx.x;
  const int lane_sw = n & 31;
  const int wrow = n * 32;

  if (n < 20) fb[n] = basis[19 - n];
  const float bias_n = bias[n];

  // Stage weight columns [128,256) of row n into swizzled LDS (own row only;
  // slot s stored at s ^ (n&31) -> same-slot reads across a wave hit 32
  // distinct banks, 2 lanes each = conflict-free).
  {
    const float4* __restrict__ gh =
        reinterpret_cast<const float4*>(weight + (size_t)n * N_NEUR + 128);
#pragma unroll
    for (int s2 = 0; s2 < 32; ++s2) wlds4[wrow + (s2 ^ lane_sw)] = gh[s2];
  }

  // Register half: columns [0,128) as 128 named scalars.
  const float4* __restrict__ w4 =
      reinterpret_cast<const float4*>(weight + (size_t)n * N_NEUR);
  FOR32(WDECL)
  FOR32(WLOADPIN)

  float hist[20];
#pragma unroll
  for (int i = 0; i < 20; ++i) hist[i] = 0.0f;

  const uint32_t idx = (uint32_t)(s * N_NEUR + n);
  const size_t plane = (size_t)N_SAMP * T_BINS * N_NEUR;
  float* __restrict__ out_spk = out + 0 * plane + (size_t)s * T_BINS * N_NEUR + n;
  float* __restrict__ out_cnv = out + 1 * plane + (size_t)s * T_BINS * N_NEUR + n;
  float* __restrict__ out_rte = out + 2 * plane + (size_t)s * T_BINS * N_NEUR + n;

  // Prefetch step-0 subkeys into a register.
  uint32_t skreg = 0;
  if (n < 2 * J_MAX) skreg = sub[n];

  __syncthreads();  // fb visible (wlds row is thread-private; no sharing)

  for (int t = 0; t < T_BINS; ++t) {
    const int buf = t & 1;
    float* __restrict__ convbuf = convb + buf * N_NEUR;
    const float4* __restrict__ convbuf4 = reinterpret_cast<const float4*>(convbuf);
    uint32_t* __restrict__ skbuf = skb + buf * 2 * J_MAX;

    if (n < 2 * J_MAX) {
      skbuf[n] = skreg;
      const int tn = (t + 1 < T_BINS) ? t + 1 : t;
      skreg = sub[(size_t)tn * (2 * J_MAX) + n];
    }

    // conv: ascending w, unfused mul+add (order bit-locked)
    float conv = 0.0f;
#pragma unroll
    for (int w = 0; w < 20; ++w) {
#if CONV_FMA
      conv = __builtin_fmaf(fb[w], hist[w], conv);
#else
      conv = fadd_s(conv, fmul_s(fb[w], hist[w]));
#endif
    }
    convbuf[n] = conv;

#if RAW_BARRIER
    asm volatile("s_waitcnt lgkmcnt(0)\n\ts_barrier" ::: "memory");
#else
    __syncthreads();
#endif

    // z = sum_k conv[k]*W[n][k], fused FMA ascending k (order bit-locked):
    // k in [0,128) from registers, k in [128,256) from swizzled LDS.
    float zacc = 0.0f;
    FOR32(WFMA)
#pragma unroll
    for (int s2 = 0; s2 < 32; ++s2) {
      const float4 wv = wlds4[wrow + (s2 ^ lane_sw)];
      const float4 cv = convbuf4[32 + s2];
      zacc = __builtin_fmaf(cv.x, wv.x, zacc);
      zacc = __builtin_fmaf(cv.y, wv.y, zacc);
      zacc = __builtin_fmaf(cv.z, wv.z, zacc);
      zacc = __builtin_fmaf(cv.w, wv.w, zacc);
    }
    const float zb = fadd_s(zacc, bias_n);

    // lam = 1 / (1 + exp(-z))
    const float lam = 1.0f / fadd_s(1.0f, xla_expf(-zb));
    const float neg_lam = -lam;

    // Knuth Poisson, ILP-batched; values & comparison sequence unchanged.
    int r = 0;
    float S = 0.0f;
    bool done = false;
    for (int jb = 0; jb < J_MAX; jb += POISSON_BATCH) {
      float L[POISSON_BATCH];
#pragma unroll
      for (int q = 0; q < POISSON_BATCH; ++q) {
        const int j = jb + q;
        uint32_t o0, o1;
        threefry2x32(skbuf[2 * j], skbuf[2 * j + 1], 0u, idx, o0, o1);
#if BITS32_XOR
        const uint32_t bits = o0 ^ o1;
#else
        const uint32_t bits = o1;
#endif
        const float u = __uint_as_float((bits >> 9) | 0x3f800000u) - 1.0f;
        L[q] = xla_logf(u);
      }
#pragma unroll
      for (int q = 0; q < POISSON_BATCH; ++q) {
        if (!done) {
          S = fadd_s(S, L[q]);
          if (S > neg_lam) ++r; else done = true;
        }
      }
      if (__all(done)) break;
    }
    const float spk = (float)r;

#pragma unroll
    for (int i = 0; i < 19; ++i) hist[i] = hist[i + 1];
    hist[19] = spk;

    const size_t off = (size_t)t * N_NEUR;
#if NT_STORES
    __builtin_nontemporal_store(spk,  out_spk + off);
    __builtin_nontemporal_store(conv, out_cnv + off);
    __builtin_nontemporal_store(lam,  out_rte + off);
#else
    out_spk[off] = spk;
    out_cnv[off] = conv;
    out_rte[off] = lam;
#endif
#if !RAW_BARRIER
    __syncthreads();
#endif
  }
}

extern "C" void kernel_launch(void* const* d_in, const int* in_sizes, int n_in,
                              void* d_out, int out_size, void* d_ws, size_t ws_size,
                              hipStream_t stream) {
  const float* basis  = (const float*)d_in[0];
  const float* weight = (const float*)d_in[1];
  const float* bias   = (const float*)d_in[2];
  float* out = (float*)d_out;
  uint32_t* sub = (uint32_t*)d_ws;  // 1024 * 32 * 2 * 4 = 256 KiB

  // Allow >64 KB dynamic LDS (133.7 KB; CU limit is 160 KB). Idempotent,
  // host-side attribute set — not a stream op, graph-capture safe.
  static bool attr_done = false;
  hipFuncSetAttribute(reinterpret_cast<const void*>(poglm_main),
                      hipFuncAttributeMaxDynamicSharedMemorySize, LDS_BYTES);
  (void)attr_done;

  hipLaunchKernelGGL(poglm_subkeys, dim3((T_BINS + 255) / 256), dim3(256), 0, stream, sub);
  hipLaunchKernelGGL(poglm_main, dim3(N_SAMP), dim3(256), LDS_BYTES, stream,
                     basis, weight, bias, sub, out);
}

// Round 7
// 3831.387 us; speedup vs baseline: 1.2405x; 1.0287x over previous
//
#include <hip/hip_runtime.h>
#include <stdint.h>
#include <math.h>

// ============================================================================
// POGLM.sample — bit-exact replication of the JAX-CPU reference.
// R7: weight columns [0,128) held in AGPRs with CLASS-CONSTRAINED def AND
//     uses (v_accvgpr_write at init, volatile v_accvgpr_read at each use).
//     R2-R6 lesson: a def-site pin is defeated when uses are plain C (the
//     allocator splits the range into VGPR class and demotes); constraining
//     every use to "a" leaves no VGPR-class segment to split.
//     Columns [128,256) in XOR-swizzled LDS (R6, 0 bank conflicts).
//     Arithmetic identical to passing R1-R6 (absmax 0.0625).
// Variant knobs:
#define THREEFRY_PARTITIONABLE 1
#define BITS32_XOR 1
#define VSL_FMA 0
#define CONV_FMA 0
#define RAW_BARRIER 1
#define POISSON_BATCH 4
#define NT_STORES 1
// ============================================================================

#define T_BINS 1024
#define N_SAMP 64
#define N_NEUR 256
#define J_MAX 32

// Dynamic LDS layout (bytes):
//   [0, 131072)            wlds: [256 rows][32 float4 slots], swizzled
//   [131072, 133120)       conv: 2 buffers x 256 floats
//   [133120, 133632)       sk:   2 buffers x 64 u32
//   [133632, 133712)       fb:   20 floats
#define WLDS_BYTES  (N_NEUR * 128 * 4)
#define CONV_OFF    WLDS_BYTES
#define SK_OFF      (CONV_OFF + 2 * N_NEUR * 4)
#define FB_OFF      (SK_OFF + 2 * 2 * J_MAX * 4)
#define LDS_BYTES   (FB_OFF + 20 * 4)

// --- strict (non-contractable) f32 ops ---
static __device__ __forceinline__ float fmul_s(float a, float b) {
#pragma clang fp contract(off)
  return a * b;
}
static __device__ __forceinline__ float fadd_s(float a, float b) {
#pragma clang fp contract(off)
  return a + b;
}
static __device__ __forceinline__ float fsub_s(float a, float b) {
#pragma clang fp contract(off)
  return a - b;
}

#if VSL_FMA
#define MULADD(a, b, c) __builtin_fmaf((a), (b), (c))
#else
#define MULADD(a, b, c) fadd_s(fmul_s((a), (b)), (c))
#endif

// --- Threefry-2x32, 20 rounds (exact JAX semantics) ---
static __device__ __forceinline__ uint32_t rotl(uint32_t v, uint32_t d) {
  return (v << d) | (v >> (32u - d));
}
static __device__ __forceinline__ void threefry2x32(uint32_t k0, uint32_t k1,
                                                    uint32_t x0, uint32_t x1,
                                                    uint32_t& o0, uint32_t& o1) {
  const uint32_t k2 = k0 ^ k1 ^ 0x1BD11BDAu;
  x0 += k0; x1 += k1;
#define TF_RD(r) { x0 += x1; x1 = rotl(x1, r); x1 ^= x0; }
  TF_RD(13u) TF_RD(15u) TF_RD(26u) TF_RD(6u)
  x0 += k1; x1 += k2 + 1u;
  TF_RD(17u) TF_RD(29u) TF_RD(16u) TF_RD(24u)
  x0 += k2; x1 += k0 + 2u;
  TF_RD(13u) TF_RD(15u) TF_RD(26u) TF_RD(6u)
  x0 += k0; x1 += k1 + 3u;
  TF_RD(17u) TF_RD(29u) TF_RD(16u) TF_RD(24u)
  x0 += k1; x1 += k2 + 4u;
  TF_RD(13u) TF_RD(15u) TF_RD(26u) TF_RD(6u)
  x0 += k2; x1 += k0 + 5u;
#undef TF_RD
  o0 = x0; o1 = x1;
}

// --- XLA CPU Cephes expf (GenerateVF32Exp) ---
static __device__ __forceinline__ float xla_expf(float input) {
  float x = fminf(input, 88.3762626647950f);
  x = fmaxf(x, -88.3762626647949f);
  float fx = floorf(MULADD(x, 1.44269504088896341f, 0.5f));
  float tmp = fmul_s(0.693359375f, fx);
  float z = fmul_s(-2.12194440e-4f, fx);
  x = fsub_s(x, tmp);
  x = fsub_s(x, z);
  z = fmul_s(x, x);
  float y = MULADD(x, 1.9875691500e-4f, 1.3981999507e-3f);
  y = MULADD(y, x, 8.3334519073e-3f);
  y = MULADD(y, x, 4.1665795894e-2f);
  y = MULADD(y, x, 1.6666665459e-1f);
  y = MULADD(y, x, 5.0000001201e-1f);
  y = MULADD(y, z, x);
  y = fadd_s(1.0f, y);
  int n = (int)fx;
  float p2n = __int_as_float((uint32_t)(n + 127) << 23);
  float res = fmul_s(y, p2n);
  return fmaxf(res, input);
}

// --- XLA CPU Cephes logf (GenerateVF32Log); u in {0} U [2^-23, 1) here ---
static __device__ __forceinline__ float xla_logf(float u) {
  if (u == 0.0f) return -INFINITY;
  uint32_t b = __float_as_uint(u);
  float e = (float)((int)(b >> 23) - 127) + 1.0f;
  float m = __uint_as_float((b & 0x007fffffu) | 0x3f000000u);
  if (m < 0.707106781186547524f) {
    e = fsub_s(e, 1.0f);
    m = fadd_s(m, m);
  }
  m = fsub_s(m, 1.0f);
  float z = fmul_s(m, m);
  float y = MULADD(m, 7.0376836292e-2f, -1.1514610310e-1f);
  y = MULADD(y, m, 1.1676998740e-1f);
  y = MULADD(y, m, -1.2420140846e-1f);
  y = MULADD(y, m, 1.4249322787e-1f);
  y = MULADD(y, m, -1.6668057665e-1f);
  y = MULADD(y, m, 2.0000714765e-1f);
  y = MULADD(y, m, -2.4999993993e-1f);
  y = MULADD(y, m, 3.3333331174e-1f);
  y = fmul_s(y, m);
  y = fmul_s(y, z);
  y = MULADD(e, -2.12194440e-4f, y);
  y = MULADD(z, -0.5f, y);
  m = fadd_s(m, y);
  m = MULADD(e, 0.693359375f, m);
  return m;
}

// ============================================================================
// Kernel 1: per-time-step subkey chains. sub layout: [t][j][2] u32.
// ============================================================================
__global__ void poglm_subkeys(uint32_t* __restrict__ sub) {
  int t = blockIdx.x * blockDim.x + threadIdx.x;
  if (t >= T_BINS) return;
  uint32_t kt0, kt1;
#if THREEFRY_PARTITIONABLE
  threefry2x32(0u, 1u, 0u, (uint32_t)t, kt0, kt1);
#else
  {
    uint32_t i0 = 2u * t, i1 = 2u * t + 1u, a0, a1, b0, b1;
    if (i0 < 1024u) { threefry2x32(0u, 1u, i0, i0 + 1024u, a0, a1); kt0 = a0; }
    else            { threefry2x32(0u, 1u, i0 - 1024u, i0, a0, a1); kt0 = a1; }
    if (i1 < 1024u) { threefry2x32(0u, 1u, i1, i1 + 1024u, b0, b1); kt1 = b0; }
    else            { threefry2x32(0u, 1u, i1 - 1024u, i1, b0, b1); kt1 = b1; }
  }
#endif
  uint32_t r0 = kt0, r1 = kt1;
  for (int j = 0; j < J_MAX; ++j) {
    uint32_t s0, s1, n0, n1;
#if THREEFRY_PARTITIONABLE
    threefry2x32(r0, r1, 0u, 1u, s0, s1);
    threefry2x32(r0, r1, 0u, 0u, n0, n1);
#else
    uint32_t p00, p01, p10, p11;
    threefry2x32(r0, r1, 0u, 2u, p00, p01);
    threefry2x32(r0, r1, 1u, 3u, p10, p11);
    n0 = p00; n1 = p10;
    s0 = p01; s1 = p11;
#endif
    sub[(size_t)t * (2 * J_MAX) + 2 * j + 0] = s0;
    sub[(size_t)t * (2 * J_MAX) + 2 * j + 1] = s1;
    r0 = n0; r1 = n1;
  }
}

// ---- macro machinery: 32 x float4 = 128 AGPR-resident weights (k in [0,128))
#define FOR32(M) \
  M(0) M(1) M(2) M(3) M(4) M(5) M(6) M(7) M(8) M(9) M(10) M(11) M(12) M(13) \
  M(14) M(15) M(16) M(17) M(18) M(19) M(20) M(21) M(22) M(23) M(24) M(25)   \
  M(26) M(27) M(28) M(29) M(30) M(31)

#define WDECL(i) float wA##i, wB##i, wC##i, wD##i;

// Def: value born in AGPR class (compiler-chosen virtual AGPR).
#define WLOADPIN(i)                                                          \
  { const float4 v_ = w4[i];                                                 \
    asm volatile("v_accvgpr_write_b32 %0, %1" : "=a"(wA##i) : "v"(v_.x));    \
    asm volatile("v_accvgpr_write_b32 %0, %1" : "=a"(wB##i) : "v"(v_.y));    \
    asm volatile("v_accvgpr_write_b32 %0, %1" : "=a"(wC##i) : "v"(v_.z));    \
    asm volatile("v_accvgpr_write_b32 %0, %1" : "=a"(wD##i) : "v"(v_.w)); }

// Use: every read is "a"-constrained (volatile: no LICM hoist of 128 copies).
// Live range is AGPR end-to-end -> allocator cannot demote it to VGPR/remat.
#define WFMA(i)                                                              \
  { float wa_, wb_, wc_, wd_;                                                \
    asm volatile("v_accvgpr_read_b32 %0, %1" : "=v"(wa_) : "a"(wA##i));      \
    asm volatile("v_accvgpr_read_b32 %0, %1" : "=v"(wb_) : "a"(wB##i));      \
    asm volatile("v_accvgpr_read_b32 %0, %1" : "=v"(wc_) : "a"(wC##i));      \
    asm volatile("v_accvgpr_read_b32 %0, %1" : "=v"(wd_) : "a"(wD##i));      \
    const float4 cv_ = convbuf4[i];                                          \
    zacc = __builtin_fmaf(cv_.x, wa_, zacc);                                 \
    zacc = __builtin_fmaf(cv_.y, wb_, zacc);                                 \
    zacc = __builtin_fmaf(cv_.z, wc_, zacc);                                 \
    zacc = __builtin_fmaf(cv_.w, wd_, zacc); }

// ============================================================================
// Kernel 2: main simulation. Block = sample (64), thread = neuron (256).
// ============================================================================
__global__ __launch_bounds__(256, 1)
void poglm_main(const float* __restrict__ basis, const float* __restrict__ weight,
                const float* __restrict__ bias, const uint32_t* __restrict__ sub,
                float* __restrict__ out) {
  extern __shared__ char lds[];
  float4*   wlds4 = reinterpret_cast<float4*>(lds);                 // [256][32] swizzled
  float*    convb = reinterpret_cast<float*>(lds + CONV_OFF);       // [2][256]
  uint32_t* skb   = reinterpret_cast<uint32_t*>(lds + SK_OFF);      // [2][64]
  float*    fb    = reinterpret_cast<float*>(lds + FB_OFF);         // [20]

  const int s = blockIdx.x;
  const int n = threadIdx.x;
  const int lane_sw = n & 31;
  const int wrow = n * 32;

  if (n < 20) fb[n] = basis[19 - n];
  const float bias_n = bias[n];

  // Stage weight columns [128,256) of row n into swizzled LDS (own row only;
  // slot s2 stored at s2 ^ (n&31): same-slot reads across a wave spread over
  // all banks, 2 lanes/bank = conflict-free; measured 0 conflicts in R6).
  {
    const float4* __restrict__ gh =
        reinterpret_cast<const float4*>(weight + (size_t)n * N_NEUR + 128);
#pragma unroll
    for (int s2 = 0; s2 < 32; ++s2) wlds4[wrow + (s2 ^ lane_sw)] = gh[s2];
  }

  // Columns [0,128): 128 scalars resident in AGPRs (def+use class-locked).
  const float4* __restrict__ w4 =
      reinterpret_cast<const float4*>(weight + (size_t)n * N_NEUR);
  FOR32(WDECL)
  FOR32(WLOADPIN)

  float hist[20];
#pragma unroll
  for (int i = 0; i < 20; ++i) hist[i] = 0.0f;

  const uint32_t idx = (uint32_t)(s * N_NEUR + n);
  const size_t plane = (size_t)N_SAMP * T_BINS * N_NEUR;
  float* __restrict__ out_spk = out + 0 * plane + (size_t)s * T_BINS * N_NEUR + n;
  float* __restrict__ out_cnv = out + 1 * plane + (size_t)s * T_BINS * N_NEUR + n;
  float* __restrict__ out_rte = out + 2 * plane + (size_t)s * T_BINS * N_NEUR + n;

  // Prefetch step-0 subkeys into a register.
  uint32_t skreg = 0;
  if (n < 2 * J_MAX) skreg = sub[n];

  __syncthreads();  // fb visible (wlds row is thread-private; no sharing)

  for (int t = 0; t < T_BINS; ++t) {
    const int buf = t & 1;
    float* __restrict__ convbuf = convb + buf * N_NEUR;
    const float4* __restrict__ convbuf4 = reinterpret_cast<const float4*>(convbuf);
    uint32_t* __restrict__ skbuf = skb + buf * 2 * J_MAX;

    if (n < 2 * J_MAX) {
      skbuf[n] = skreg;
      const int tn = (t + 1 < T_BINS) ? t + 1 : t;
      skreg = sub[(size_t)tn * (2 * J_MAX) + n];
    }

    // conv: ascending w, unfused mul+add (order bit-locked)
    float conv = 0.0f;
#pragma unroll
    for (int w = 0; w < 20; ++w) {
#if CONV_FMA
      conv = __builtin_fmaf(fb[w], hist[w], conv);
#else
      conv = fadd_s(conv, fmul_s(fb[w], hist[w]));
#endif
    }
    convbuf[n] = conv;

#if RAW_BARRIER
    asm volatile("s_waitcnt lgkmcnt(0)\n\ts_barrier" ::: "memory");
#else
    __syncthreads();
#endif

    // z = sum_k conv[k]*W[n][k], fused FMA ascending k (order bit-locked):
    // k in [0,128) from AGPRs, k in [128,256) from swizzled LDS.
    float zacc = 0.0f;
    FOR32(WFMA)
#pragma unroll
    for (int s2 = 0; s2 < 32; ++s2) {
      const float4 wv = wlds4[wrow + (s2 ^ lane_sw)];
      const float4 cv = convbuf4[32 + s2];
      zacc = __builtin_fmaf(cv.x, wv.x, zacc);
      zacc = __builtin_fmaf(cv.y, wv.y, zacc);
      zacc = __builtin_fmaf(cv.z, wv.z, zacc);
      zacc = __builtin_fmaf(cv.w, wv.w, zacc);
    }
    const float zb = fadd_s(zacc, bias_n);

    // lam = 1 / (1 + exp(-z))
    const float lam = 1.0f / fadd_s(1.0f, xla_expf(-zb));
    const float neg_lam = -lam;

    // Knuth Poisson, ILP-batched; values & comparison sequence unchanged.
    int r = 0;
    float S = 0.0f;
    bool done = false;
    for (int jb = 0; jb < J_MAX; jb += POISSON_BATCH) {
      float L[POISSON_BATCH];
#pragma unroll
      for (int q = 0; q < POISSON_BATCH; ++q) {
        const int j = jb + q;
        uint32_t o0, o1;
        threefry2x32(skbuf[2 * j], skbuf[2 * j + 1], 0u, idx, o0, o1);
#if BITS32_XOR
        const uint32_t bits = o0 ^ o1;
#else
        const uint32_t bits = o1;
#endif
        const float u = __uint_as_float((bits >> 9) | 0x3f800000u) - 1.0f;
        L[q] = xla_logf(u);
      }
#pragma unroll
      for (int q = 0; q < POISSON_BATCH; ++q) {
        if (!done) {
          S = fadd_s(S, L[q]);
          if (S > neg_lam) ++r; else done = true;
        }
      }
      if (__all(done)) break;
    }
    const float spk = (float)r;

#pragma unroll
    for (int i = 0; i < 19; ++i) hist[i] = hist[i + 1];
    hist[19] = spk;

    const size_t off = (size_t)t * N_NEUR;
#if NT_STORES
    __builtin_nontemporal_store(spk,  out_spk + off);
    __builtin_nontemporal_store(conv, out_cnv + off);
    __builtin_nontemporal_store(lam,  out_rte + off);
#else
    out_spk[off] = spk;
    out_cnv[off] = conv;
    out_rte[off] = lam;
#endif
#if !RAW_BARRIER
    __syncthreads();
#endif
  }
}

extern "C" void kernel_launch(void* const* d_in, const int* in_sizes, int n_in,
                              void* d_out, int out_size, void* d_ws, size_t ws_size,
                              hipStream_t stream) {
  const float* basis  = (const float*)d_in[0];
  const float* weight = (const float*)d_in[1];
  const float* bias   = (const float*)d_in[2];
  float* out = (float*)d_out;
  uint32_t* sub = (uint32_t*)d_ws;  // 1024 * 32 * 2 * 4 = 256 KiB

  // Allow >64 KB dynamic LDS (133.7 KB; CU limit 160 KB). Host-side attr,
  // graph-capture safe; worked in R6 (kernel ran with 133 KB).
  hipFuncSetAttribute(reinterpret_cast<const void*>(poglm_main),
                      hipFuncAttributeMaxDynamicSharedMemorySize, LDS_BYTES);

  hipLaunchKernelGGL(poglm_subkeys, dim3((T_BINS + 255) / 256), dim3(256), 0, stream, sub);
  hipLaunchKernelGGL(poglm_main, dim3(N_SAMP), dim3(256), LDS_BYTES, stream,
                     basis, weight, bias, sub, out);
}

// Round 8
// 3748.016 us; speedup vs baseline: 1.2680x; 1.0222x over previous
//
#include <hip/hip_runtime.h>
#include <stdint.h>
#include <math.h>

// ============================================================================
// POGLM.sample — bit-exact replication of the JAX-CPU reference.
// R8: (1) chunked z-phase — batch-issue 8 ds_read_b128 per chunk ahead of the
//     volatile AGPR reads/FMAs (R7 exposed ~32 LDS latencies per step);
//     (2) rolled Poisson loop (#pragma unroll 1) — R7's unrolled body was
//     ~30KB, thrashing the 32KB L1I every iteration (suspected source of the
//     constant ~2.1GB FETCH). Arithmetic identical to passing R1-R7.
// Variant knobs:
#define THREEFRY_PARTITIONABLE 1
#define BITS32_XOR 1
#define VSL_FMA 0
#define CONV_FMA 0
#define RAW_BARRIER 1
#define POISSON_BATCH 4
#define NT_STORES 1
// ============================================================================

#define T_BINS 1024
#define N_SAMP 64
#define N_NEUR 256
#define J_MAX 32

// Dynamic LDS layout (bytes):
#define WLDS_BYTES  (N_NEUR * 128 * 4)
#define CONV_OFF    WLDS_BYTES
#define SK_OFF      (CONV_OFF + 2 * N_NEUR * 4)
#define FB_OFF      (SK_OFF + 2 * 2 * J_MAX * 4)
#define LDS_BYTES   (FB_OFF + 20 * 4)

// --- strict (non-contractable) f32 ops ---
static __device__ __forceinline__ float fmul_s(float a, float b) {
#pragma clang fp contract(off)
  return a * b;
}
static __device__ __forceinline__ float fadd_s(float a, float b) {
#pragma clang fp contract(off)
  return a + b;
}
static __device__ __forceinline__ float fsub_s(float a, float b) {
#pragma clang fp contract(off)
  return a - b;
}

#if VSL_FMA
#define MULADD(a, b, c) __builtin_fmaf((a), (b), (c))
#else
#define MULADD(a, b, c) fadd_s(fmul_s((a), (b)), (c))
#endif

// --- Threefry-2x32, 20 rounds (exact JAX semantics) ---
static __device__ __forceinline__ uint32_t rotl(uint32_t v, uint32_t d) {
  return (v << d) | (v >> (32u - d));
}
static __device__ __forceinline__ void threefry2x32(uint32_t k0, uint32_t k1,
                                                    uint32_t x0, uint32_t x1,
                                                    uint32_t& o0, uint32_t& o1) {
  const uint32_t k2 = k0 ^ k1 ^ 0x1BD11BDAu;
  x0 += k0; x1 += k1;
#define TF_RD(r) { x0 += x1; x1 = rotl(x1, r); x1 ^= x0; }
  TF_RD(13u) TF_RD(15u) TF_RD(26u) TF_RD(6u)
  x0 += k1; x1 += k2 + 1u;
  TF_RD(17u) TF_RD(29u) TF_RD(16u) TF_RD(24u)
  x0 += k2; x1 += k0 + 2u;
  TF_RD(13u) TF_RD(15u) TF_RD(26u) TF_RD(6u)
  x0 += k0; x1 += k1 + 3u;
  TF_RD(17u) TF_RD(29u) TF_RD(16u) TF_RD(24u)
  x0 += k1; x1 += k2 + 4u;
  TF_RD(13u) TF_RD(15u) TF_RD(26u) TF_RD(6u)
  x0 += k2; x1 += k0 + 5u;
#undef TF_RD
  o0 = x0; o1 = x1;
}

// --- XLA CPU Cephes expf (GenerateVF32Exp) ---
static __device__ __forceinline__ float xla_expf(float input) {
  float x = fminf(input, 88.3762626647950f);
  x = fmaxf(x, -88.3762626647949f);
  float fx = floorf(MULADD(x, 1.44269504088896341f, 0.5f));
  float tmp = fmul_s(0.693359375f, fx);
  float z = fmul_s(-2.12194440e-4f, fx);
  x = fsub_s(x, tmp);
  x = fsub_s(x, z);
  z = fmul_s(x, x);
  float y = MULADD(x, 1.9875691500e-4f, 1.3981999507e-3f);
  y = MULADD(y, x, 8.3334519073e-3f);
  y = MULADD(y, x, 4.1665795894e-2f);
  y = MULADD(y, x, 1.6666665459e-1f);
  y = MULADD(y, x, 5.0000001201e-1f);
  y = MULADD(y, z, x);
  y = fadd_s(1.0f, y);
  int n = (int)fx;
  float p2n = __int_as_float((uint32_t)(n + 127) << 23);
  float res = fmul_s(y, p2n);
  return fmaxf(res, input);
}

// --- XLA CPU Cephes logf (GenerateVF32Log); u in {0} U [2^-23, 1) here ---
static __device__ __forceinline__ float xla_logf(float u) {
  if (u == 0.0f) return -INFINITY;
  uint32_t b = __float_as_uint(u);
  float e = (float)((int)(b >> 23) - 127) + 1.0f;
  float m = __uint_as_float((b & 0x007fffffu) | 0x3f000000u);
  if (m < 0.707106781186547524f) {
    e = fsub_s(e, 1.0f);
    m = fadd_s(m, m);
  }
  m = fsub_s(m, 1.0f);
  float z = fmul_s(m, m);
  float y = MULADD(m, 7.0376836292e-2f, -1.1514610310e-1f);
  y = MULADD(y, m, 1.1676998740e-1f);
  y = MULADD(y, m, -1.2420140846e-1f);
  y = MULADD(y, m, 1.4249322787e-1f);
  y = MULADD(y, m, -1.6668057665e-1f);
  y = MULADD(y, m, 2.0000714765e-1f);
  y = MULADD(y, m, -2.4999993993e-1f);
  y = MULADD(y, m, 3.3333331174e-1f);
  y = fmul_s(y, m);
  y = fmul_s(y, z);
  y = MULADD(e, -2.12194440e-4f, y);
  y = MULADD(z, -0.5f, y);
  m = fadd_s(m, y);
  m = MULADD(e, 0.693359375f, m);
  return m;
}

// ============================================================================
// Kernel 1: per-time-step subkey chains. sub layout: [t][j][2] u32.
// ============================================================================
__global__ void poglm_subkeys(uint32_t* __restrict__ sub) {
  int t = blockIdx.x * blockDim.x + threadIdx.x;
  if (t >= T_BINS) return;
  uint32_t kt0, kt1;
#if THREEFRY_PARTITIONABLE
  threefry2x32(0u, 1u, 0u, (uint32_t)t, kt0, kt1);
#else
  {
    uint32_t i0 = 2u * t, i1 = 2u * t + 1u, a0, a1, b0, b1;
    if (i0 < 1024u) { threefry2x32(0u, 1u, i0, i0 + 1024u, a0, a1); kt0 = a0; }
    else            { threefry2x32(0u, 1u, i0 - 1024u, i0, a0, a1); kt0 = a1; }
    if (i1 < 1024u) { threefry2x32(0u, 1u, i1, i1 + 1024u, b0, b1); kt1 = b0; }
    else            { threefry2x32(0u, 1u, i1 - 1024u, i1, b0, b1); kt1 = b1; }
  }
#endif
  uint32_t r0 = kt0, r1 = kt1;
  for (int j = 0; j < J_MAX; ++j) {
    uint32_t s0, s1, n0, n1;
#if THREEFRY_PARTITIONABLE
    threefry2x32(r0, r1, 0u, 1u, s0, s1);
    threefry2x32(r0, r1, 0u, 0u, n0, n1);
#else
    uint32_t p00, p01, p10, p11;
    threefry2x32(r0, r1, 0u, 2u, p00, p01);
    threefry2x32(r0, r1, 1u, 3u, p10, p11);
    n0 = p00; n1 = p10;
    s0 = p01; s1 = p11;
#endif
    sub[(size_t)t * (2 * J_MAX) + 2 * j + 0] = s0;
    sub[(size_t)t * (2 * J_MAX) + 2 * j + 1] = s1;
    r0 = n0; r1 = n1;
  }
}

// ---- 32 x float4 = 128 AGPR-resident weights (k in [0,128)) ----------------
#define FOR32(M) \
  M(0) M(1) M(2) M(3) M(4) M(5) M(6) M(7) M(8) M(9) M(10) M(11) M(12) M(13) \
  M(14) M(15) M(16) M(17) M(18) M(19) M(20) M(21) M(22) M(23) M(24) M(25)   \
  M(26) M(27) M(28) M(29) M(30) M(31)

#define WDECL(i) float wA##i, wB##i, wC##i, wD##i;

#define WLOADPIN(i)                                                          \
  { const float4 v_ = w4[i];                                                 \
    asm volatile("v_accvgpr_write_b32 %0, %1" : "=a"(wA##i) : "v"(v_.x));    \
    asm volatile("v_accvgpr_write_b32 %0, %1" : "=a"(wB##i) : "v"(v_.y));    \
    asm volatile("v_accvgpr_write_b32 %0, %1" : "=a"(wC##i) : "v"(v_.z));    \
    asm volatile("v_accvgpr_write_b32 %0, %1" : "=a"(wD##i) : "v"(v_.w)); }

// Chunked z-phase: issue 8 independent ds_read_b128 first, THEN the volatile
// AGPR reads + FMAs (k-ascending order preserved exactly).
#define LOADCV(u, i) const float4 cv##u = convbuf4[i];
#define AFMA(u, i)                                                           \
  { float wa_, wb_, wc_, wd_;                                                \
    asm volatile("v_accvgpr_read_b32 %0, %1" : "=v"(wa_) : "a"(wA##i));      \
    asm volatile("v_accvgpr_read_b32 %0, %1" : "=v"(wb_) : "a"(wB##i));      \
    asm volatile("v_accvgpr_read_b32 %0, %1" : "=v"(wc_) : "a"(wC##i));      \
    asm volatile("v_accvgpr_read_b32 %0, %1" : "=v"(wd_) : "a"(wD##i));      \
    zacc = __builtin_fmaf(cv##u.x, wa_, zacc);                               \
    zacc = __builtin_fmaf(cv##u.y, wb_, zacc);                               \
    zacc = __builtin_fmaf(cv##u.z, wc_, zacc);                               \
    zacc = __builtin_fmaf(cv##u.w, wd_, zacc); }

#define ZCHUNK(i0,i1,i2,i3,i4,i5,i6,i7)                                      \
  { LOADCV(0,i0) LOADCV(1,i1) LOADCV(2,i2) LOADCV(3,i3)                      \
    LOADCV(4,i4) LOADCV(5,i5) LOADCV(6,i6) LOADCV(7,i7)                      \
    AFMA(0,i0) AFMA(1,i1) AFMA(2,i2) AFMA(3,i3)                              \
    AFMA(4,i4) AFMA(5,i5) AFMA(6,i6) AFMA(7,i7) }

// ============================================================================
// Kernel 2: main simulation. Block = sample (64), thread = neuron (256).
// ============================================================================
__global__ __launch_bounds__(256, 1)
void poglm_main(const float* __restrict__ basis, const float* __restrict__ weight,
                const float* __restrict__ bias, const uint32_t* __restrict__ sub,
                float* __restrict__ out) {
  extern __shared__ char lds[];
  float4*   wlds4 = reinterpret_cast<float4*>(lds);                 // [256][32] swizzled
  float*    convb = reinterpret_cast<float*>(lds + CONV_OFF);       // [2][256]
  uint32_t* skb   = reinterpret_cast<uint32_t*>(lds + SK_OFF);      // [2][64]
  float*    fb    = reinterpret_cast<float*>(lds + FB_OFF);         // [20]

  const int s = blockIdx.x;
  const int n = threadIdx.x;
  const int lane_sw = n & 31;
  const int wrow = n * 32;

  if (n < 20) fb[n] = basis[19 - n];
  const float bias_n = bias[n];

  // Stage weight columns [128,256) of row n into swizzled LDS (own row only).
  {
    const float4* __restrict__ gh =
        reinterpret_cast<const float4*>(weight + (size_t)n * N_NEUR + 128);
#pragma unroll
    for (int s2 = 0; s2 < 32; ++s2) wlds4[wrow + (s2 ^ lane_sw)] = gh[s2];
  }

  // Columns [0,128): 128 scalars resident in AGPRs (def+use class-locked).
  const float4* __restrict__ w4 =
      reinterpret_cast<const float4*>(weight + (size_t)n * N_NEUR);
  FOR32(WDECL)
  FOR32(WLOADPIN)

  float hist[20];
#pragma unroll
  for (int i = 0; i < 20; ++i) hist[i] = 0.0f;

  const uint32_t idx = (uint32_t)(s * N_NEUR + n);
  const size_t plane = (size_t)N_SAMP * T_BINS * N_NEUR;
  float* __restrict__ out_spk = out + 0 * plane + (size_t)s * T_BINS * N_NEUR + n;
  float* __restrict__ out_cnv = out + 1 * plane + (size_t)s * T_BINS * N_NEUR + n;
  float* __restrict__ out_rte = out + 2 * plane + (size_t)s * T_BINS * N_NEUR + n;

  // Prefetch step-0 subkeys into a register.
  uint32_t skreg = 0;
  if (n < 2 * J_MAX) skreg = sub[n];

  __syncthreads();  // fb visible

  for (int t = 0; t < T_BINS; ++t) {
    const int buf = t & 1;
    float* __restrict__ convbuf = convb + buf * N_NEUR;
    const float4* __restrict__ convbuf4 = reinterpret_cast<const float4*>(convbuf);
    uint32_t* __restrict__ skbuf = skb + buf * 2 * J_MAX;

    if (n < 2 * J_MAX) {
      skbuf[n] = skreg;
      const int tn = (t + 1 < T_BINS) ? t + 1 : t;
      skreg = sub[(size_t)tn * (2 * J_MAX) + n];
    }

    // conv: ascending w, unfused mul+add (order bit-locked)
    float conv = 0.0f;
#pragma unroll
    for (int w = 0; w < 20; ++w) {
#if CONV_FMA
      conv = __builtin_fmaf(fb[w], hist[w], conv);
#else
      conv = fadd_s(conv, fmul_s(fb[w], hist[w]));
#endif
    }
    convbuf[n] = conv;

#if RAW_BARRIER
    asm volatile("s_waitcnt lgkmcnt(0)\n\ts_barrier" ::: "memory");
#else
    __syncthreads();
#endif

    // z = sum_k conv[k]*W[n][k], fused FMA ascending k (order bit-locked):
    // k in [0,128) from AGPRs (4 chunks of 8 batched ds_reads),
    // k in [128,256) from swizzled LDS (4 chunks of 8+8 batched ds_reads).
    float zacc = 0.0f;
    ZCHUNK(0,1,2,3,4,5,6,7)
    ZCHUNK(8,9,10,11,12,13,14,15)
    ZCHUNK(16,17,18,19,20,21,22,23)
    ZCHUNK(24,25,26,27,28,29,30,31)
#pragma unroll
    for (int c2 = 0; c2 < 4; ++c2) {
      float4 wv[8], cv[8];
#pragma unroll
      for (int u = 0; u < 8; ++u) {
        const int s2 = 8 * c2 + u;
        wv[u] = wlds4[wrow + (s2 ^ lane_sw)];
        cv[u] = convbuf4[32 + s2];
      }
#pragma unroll
      for (int u = 0; u < 8; ++u) {
        zacc = __builtin_fmaf(cv[u].x, wv[u].x, zacc);
        zacc = __builtin_fmaf(cv[u].y, wv[u].y, zacc);
        zacc = __builtin_fmaf(cv[u].z, wv[u].z, zacc);
        zacc = __builtin_fmaf(cv[u].w, wv[u].w, zacc);
      }
    }
    const float zb = fadd_s(zacc, bias_n);

    // lam = 1 / (1 + exp(-z))
    const float lam = 1.0f / fadd_s(1.0f, xla_expf(-zb));
    const float neg_lam = -lam;

    // Knuth Poisson, ILP-batched, ROLLED outer loop (code size: the unrolled
    // form was ~30KB of instructions, thrashing L1I every t-iteration).
    int r = 0;
    float S = 0.0f;
    bool done = false;
#pragma unroll 1
    for (int jb = 0; jb < J_MAX; jb += POISSON_BATCH) {
      float L[POISSON_BATCH];
#pragma unroll
      for (int q = 0; q < POISSON_BATCH; ++q) {
        const int j = jb + q;
        uint32_t o0, o1;
        threefry2x32(skbuf[2 * j], skbuf[2 * j + 1], 0u, idx, o0, o1);
#if BITS32_XOR
        const uint32_t bits = o0 ^ o1;
#else
        const uint32_t bits = o1;
#endif
        const float u = __uint_as_float((bits >> 9) | 0x3f800000u) - 1.0f;
        L[q] = xla_logf(u);
      }
#pragma unroll
      for (int q = 0; q < POISSON_BATCH; ++q) {
        if (!done) {
          S = fadd_s(S, L[q]);
          if (S > neg_lam) ++r; else done = true;
        }
      }
      if (__all(done)) break;
    }
    const float spk = (float)r;

#pragma unroll
    for (int i = 0; i < 19; ++i) hist[i] = hist[i + 1];
    hist[19] = spk;

    const size_t off = (size_t)t * N_NEUR;
#if NT_STORES
    __builtin_nontemporal_store(spk,  out_spk + off);
    __builtin_nontemporal_store(conv, out_cnv + off);
    __builtin_nontemporal_store(lam,  out_rte + off);
#else
    out_spk[off] = spk;
    out_cnv[off] = conv;
    out_rte[off] = lam;
#endif
#if !RAW_BARRIER
    __syncthreads();
#endif
  }
}

extern "C" void kernel_launch(void* const* d_in, const int* in_sizes, int n_in,
                              void* d_out, int out_size, void* d_ws, size_t ws_size,
                              hipStream_t stream) {
  const float* basis  = (const float*)d_in[0];
  const float* weight = (const float*)d_in[1];
  const float* bias   = (const float*)d_in[2];
  float* out = (float*)d_out;
  uint32_t* sub = (uint32_t*)d_ws;  // 1024 * 32 * 2 * 4 = 256 KiB

  hipFuncSetAttribute(reinterpret_cast<const void*>(poglm_main),
                      hipFuncAttributeMaxDynamicSharedMemorySize, LDS_BYTES);

  hipLaunchKernelGGL(poglm_subkeys, dim3((T_BINS + 255) / 256), dim3(256), 0, stream, sub);
  hipLaunchKernelGGL(poglm_main, dim3(N_SAMP), dim3(256), LDS_BYTES, stream,
                     basis, weight, bias, sub, out);
}

// Round 9
// 2500.966 us; speedup vs baseline: 1.9003x; 1.4986x over previous
//
#include <hip/hip_runtime.h>
#include <stdint.h>
#include <math.h>

// ============================================================================
// POGLM.sample — bit-exact replication of the JAX-CPU reference.
// R9: Poisson prefix sums S_j (j=1..8) are key-only -> precomputed by a
//     device-filling kernel into d_ws; main kernel counts S_j > -lam (exact by
//     monotonicity) + rare inline continuation from S_8 (P<=1e-5/lane-step).
//     Removes ~half of main-loop VALU issue (threefry) + wave skew.
//     T-chunked if ws is small; inline fallback if ws too small (R8 path).
// Variant knobs:
#define THREEFRY_PARTITIONABLE 1
#define BITS32_XOR 1
#define VSL_FMA 0
#define CONV_FMA 0
#define RAW_BARRIER 1
#define POISSON_BATCH 4   // inline-path batch
#define NT_STORES 1
#define J_PRE 8           // precomputed prefix depth
// ============================================================================

#define T_BINS 1024
#define N_SAMP 64
#define N_NEUR 256
#define J_MAX 32
#define LANES (N_SAMP * N_NEUR)  // 16384

// Dynamic LDS layout (main kernel), same as R8:
#define WLDS_BYTES  (N_NEUR * 128 * 4)
#define CONV_OFF    WLDS_BYTES
#define SK_OFF      (CONV_OFF + 2 * N_NEUR * 4)
#define FB_OFF      (SK_OFF + 2 * 2 * J_MAX * 4)
#define LDS_BYTES   (FB_OFF + 20 * 4)

// d_ws layout:
//   [0, 256KB)                     sub:  [1024][32][2] u32
//   [256KB, 256KB+1.25MB)          hist: [20][16384] f32 (chunk handoff)
//   [STBL_OFF, ...)                S-table: [chunkT][16384][8] f32
#define SUB_BYTES   (T_BINS * 2 * J_MAX * 4)
#define HIST_OFF    SUB_BYTES
#define HIST_BYTES  (20 * LANES * 4)
#define STBL_OFF    (HIST_OFF + HIST_BYTES)

// --- strict (non-contractable) f32 ops ---
static __device__ __forceinline__ float fmul_s(float a, float b) {
#pragma clang fp contract(off)
  return a * b;
}
static __device__ __forceinline__ float fadd_s(float a, float b) {
#pragma clang fp contract(off)
  return a + b;
}
static __device__ __forceinline__ float fsub_s(float a, float b) {
#pragma clang fp contract(off)
  return a - b;
}

#if VSL_FMA
#define MULADD(a, b, c) __builtin_fmaf((a), (b), (c))
#else
#define MULADD(a, b, c) fadd_s(fmul_s((a), (b)), (c))
#endif

// --- Threefry-2x32, 20 rounds (exact JAX semantics) ---
static __device__ __forceinline__ uint32_t rotl(uint32_t v, uint32_t d) {
  return (v << d) | (v >> (32u - d));
}
static __device__ __forceinline__ void threefry2x32(uint32_t k0, uint32_t k1,
                                                    uint32_t x0, uint32_t x1,
                                                    uint32_t& o0, uint32_t& o1) {
  const uint32_t k2 = k0 ^ k1 ^ 0x1BD11BDAu;
  x0 += k0; x1 += k1;
#define TF_RD(r) { x0 += x1; x1 = rotl(x1, r); x1 ^= x0; }
  TF_RD(13u) TF_RD(15u) TF_RD(26u) TF_RD(6u)
  x0 += k1; x1 += k2 + 1u;
  TF_RD(17u) TF_RD(29u) TF_RD(16u) TF_RD(24u)
  x0 += k2; x1 += k0 + 2u;
  TF_RD(13u) TF_RD(15u) TF_RD(26u) TF_RD(6u)
  x0 += k0; x1 += k1 + 3u;
  TF_RD(17u) TF_RD(29u) TF_RD(16u) TF_RD(24u)
  x0 += k1; x1 += k2 + 4u;
  TF_RD(13u) TF_RD(15u) TF_RD(26u) TF_RD(6u)
  x0 += k2; x1 += k0 + 5u;
#undef TF_RD
  o0 = x0; o1 = x1;
}

// --- XLA CPU Cephes expf (GenerateVF32Exp) ---
static __device__ __forceinline__ float xla_expf(float input) {
  float x = fminf(input, 88.3762626647950f);
  x = fmaxf(x, -88.3762626647949f);
  float fx = floorf(MULADD(x, 1.44269504088896341f, 0.5f));
  float tmp = fmul_s(0.693359375f, fx);
  float z = fmul_s(-2.12194440e-4f, fx);
  x = fsub_s(x, tmp);
  x = fsub_s(x, z);
  z = fmul_s(x, x);
  float y = MULADD(x, 1.9875691500e-4f, 1.3981999507e-3f);
  y = MULADD(y, x, 8.3334519073e-3f);
  y = MULADD(y, x, 4.1665795894e-2f);
  y = MULADD(y, x, 1.6666665459e-1f);
  y = MULADD(y, x, 5.0000001201e-1f);
  y = MULADD(y, z, x);
  y = fadd_s(1.0f, y);
  int n = (int)fx;
  float p2n = __int_as_float((uint32_t)(n + 127) << 23);
  float res = fmul_s(y, p2n);
  return fmaxf(res, input);
}

// --- XLA CPU Cephes logf (GenerateVF32Log); u in {0} U [2^-23, 1) here ---
static __device__ __forceinline__ float xla_logf(float u) {
  if (u == 0.0f) return -INFINITY;
  uint32_t b = __float_as_uint(u);
  float e = (float)((int)(b >> 23) - 127) + 1.0f;
  float m = __uint_as_float((b & 0x007fffffu) | 0x3f000000u);
  if (m < 0.707106781186547524f) {
    e = fsub_s(e, 1.0f);
    m = fadd_s(m, m);
  }
  m = fsub_s(m, 1.0f);
  float z = fmul_s(m, m);
  float y = MULADD(m, 7.0376836292e-2f, -1.1514610310e-1f);
  y = MULADD(y, m, 1.1676998740e-1f);
  y = MULADD(y, m, -1.2420140846e-1f);
  y = MULADD(y, m, 1.4249322787e-1f);
  y = MULADD(y, m, -1.6668057665e-1f);
  y = MULADD(y, m, 2.0000714765e-1f);
  y = MULADD(y, m, -2.4999993993e-1f);
  y = MULADD(y, m, 3.3333331174e-1f);
  y = fmul_s(y, m);
  y = fmul_s(y, z);
  y = MULADD(e, -2.12194440e-4f, y);
  y = MULADD(z, -0.5f, y);
  m = fadd_s(m, y);
  m = MULADD(e, 0.693359375f, m);
  return m;
}

// ============================================================================
// Kernel 1: per-time-step subkey chains. sub layout: [t][j][2] u32.
// ============================================================================
__global__ void poglm_subkeys(uint32_t* __restrict__ sub) {
  int t = blockIdx.x * blockDim.x + threadIdx.x;
  if (t >= T_BINS) return;
  uint32_t kt0, kt1;
#if THREEFRY_PARTITIONABLE
  threefry2x32(0u, 1u, 0u, (uint32_t)t, kt0, kt1);
#else
  {
    uint32_t i0 = 2u * t, i1 = 2u * t + 1u, a0, a1, b0, b1;
    if (i0 < 1024u) { threefry2x32(0u, 1u, i0, i0 + 1024u, a0, a1); kt0 = a0; }
    else            { threefry2x32(0u, 1u, i0 - 1024u, i0, a0, a1); kt0 = a1; }
    if (i1 < 1024u) { threefry2x32(0u, 1u, i1, i1 + 1024u, b0, b1); kt1 = b0; }
    else            { threefry2x32(0u, 1u, i1 - 1024u, i1, b0, b1); kt1 = b1; }
  }
#endif
  uint32_t r0 = kt0, r1 = kt1;
  for (int j = 0; j < J_MAX; ++j) {
    uint32_t s0, s1, n0, n1;
#if THREEFRY_PARTITIONABLE
    threefry2x32(r0, r1, 0u, 1u, s0, s1);
    threefry2x32(r0, r1, 0u, 0u, n0, n1);
#else
    uint32_t p00, p01, p10, p11;
    threefry2x32(r0, r1, 0u, 2u, p00, p01);
    threefry2x32(r0, r1, 1u, 3u, p10, p11);
    n0 = p00; n1 = p10;
    s0 = p01; s1 = p11;
#endif
    sub[(size_t)t * (2 * J_MAX) + 2 * j + 0] = s0;
    sub[(size_t)t * (2 * J_MAX) + 2 * j + 1] = s1;
    r0 = n0; r1 = n1;
  }
}

// ============================================================================
// Kernel 1b: S-prefix table. One thread per (t, s, n); 8 draws, byte-identical
// chain S_j = fadd_s(S_{j-1}, xla_logf(u_j)). Grid fills the whole device.
// Layout: S8[((t-t0)*LANES + idx)*8 + j].
// ============================================================================
__global__ __launch_bounds__(256)
void poglm_stable(const uint32_t* __restrict__ sub, float* __restrict__ S8,
                  int t0) {
  const int g   = blockIdx.x * 256 + threadIdx.x;
  const int tt  = t0 + g / LANES;       // 64 blocks per t; no block straddles t
  const int ln  = g % LANES;            // = s*256+n = idx
  float S = 0.0f;
  float v[J_PRE];
#pragma unroll
  for (int j = 0; j < J_PRE; ++j) {
    const uint32_t k0 = sub[(size_t)tt * (2 * J_MAX) + 2 * j];
    const uint32_t k1 = sub[(size_t)tt * (2 * J_MAX) + 2 * j + 1];
    uint32_t o0, o1;
    threefry2x32(k0, k1, 0u, (uint32_t)ln, o0, o1);
#if BITS32_XOR
    const uint32_t bits = o0 ^ o1;
#else
    const uint32_t bits = o1;
#endif
    const float u = __uint_as_float((bits >> 9) | 0x3f800000u) - 1.0f;
    S = fadd_s(S, xla_logf(u));
    v[j] = S;
  }
  float4* dst = reinterpret_cast<float4*>(S8 + (size_t)g * J_PRE);
  dst[0] = make_float4(v[0], v[1], v[2], v[3]);
  dst[1] = make_float4(v[4], v[5], v[6], v[7]);
}

// ---- 32 x float4 = 128 AGPR-resident weights (k in [0,128)) ----------------
#define FOR32(M) \
  M(0) M(1) M(2) M(3) M(4) M(5) M(6) M(7) M(8) M(9) M(10) M(11) M(12) M(13) \
  M(14) M(15) M(16) M(17) M(18) M(19) M(20) M(21) M(22) M(23) M(24) M(25)   \
  M(26) M(27) M(28) M(29) M(30) M(31)

#define WDECL(i) float wA##i, wB##i, wC##i, wD##i;

#define WLOADPIN(i)                                                          \
  { const float4 v_ = w4[i];                                                 \
    asm volatile("v_accvgpr_write_b32 %0, %1" : "=a"(wA##i) : "v"(v_.x));    \
    asm volatile("v_accvgpr_write_b32 %0, %1" : "=a"(wB##i) : "v"(v_.y));    \
    asm volatile("v_accvgpr_write_b32 %0, %1" : "=a"(wC##i) : "v"(v_.z));    \
    asm volatile("v_accvgpr_write_b32 %0, %1" : "=a"(wD##i) : "v"(v_.w)); }

#define LOADCV(u, i) const float4 cv##u = convbuf4[i];
#define AFMA(u, i)                                                           \
  { float wa_, wb_, wc_, wd_;                                                \
    asm volatile("v_accvgpr_read_b32 %0, %1" : "=v"(wa_) : "a"(wA##i));      \
    asm volatile("v_accvgpr_read_b32 %0, %1" : "=v"(wb_) : "a"(wB##i));      \
    asm volatile("v_accvgpr_read_b32 %0, %1" : "=v"(wc_) : "a"(wC##i));      \
    asm volatile("v_accvgpr_read_b32 %0, %1" : "=v"(wd_) : "a"(wD##i));      \
    zacc = __builtin_fmaf(cv##u.x, wa_, zacc);                               \
    zacc = __builtin_fmaf(cv##u.y, wb_, zacc);                               \
    zacc = __builtin_fmaf(cv##u.z, wc_, zacc);                               \
    zacc = __builtin_fmaf(cv##u.w, wd_, zacc); }

#define ZCHUNK(i0,i1,i2,i3,i4,i5,i6,i7)                                      \
  { LOADCV(0,i0) LOADCV(1,i1) LOADCV(2,i2) LOADCV(3,i3)                      \
    LOADCV(4,i4) LOADCV(5,i5) LOADCV(6,i6) LOADCV(7,i7)                      \
    AFMA(0,i0) AFMA(1,i1) AFMA(2,i2) AFMA(3,i3)                              \
    AFMA(4,i4) AFMA(5,i5) AFMA(6,i6) AFMA(7,i7) }

// ============================================================================
// Kernel 2: main simulation over [t0, t1). MODE 1 = S-table Poisson (+ rare
// inline continuation); MODE 0 = R8 inline Poisson. hist handed off via ws
// when chunked.
// ============================================================================
template <int MODE>
__global__ __launch_bounds__(256, 1)
void poglm_main(const float* __restrict__ basis, const float* __restrict__ weight,
                const float* __restrict__ bias, const uint32_t* __restrict__ sub,
                float* __restrict__ out, const float* __restrict__ S8,
                float* __restrict__ histws, int t0, int t1) {
  extern __shared__ char lds[];
  float4*   wlds4 = reinterpret_cast<float4*>(lds);                 // [256][32] swizzled
  float*    convb = reinterpret_cast<float*>(lds + CONV_OFF);       // [2][256]
  uint32_t* skb   = reinterpret_cast<uint32_t*>(lds + SK_OFF);      // [2][64] (MODE 0)
  float*    fb    = reinterpret_cast<float*>(lds + FB_OFF);         // [20]

  const int s = blockIdx.x;
  const int n = threadIdx.x;
  const int lane_sw = n & 31;
  const int wrow = n * 32;

  if (n < 20) fb[n] = basis[19 - n];
  const float bias_n = bias[n];

  // Stage weight columns [128,256) of row n into swizzled LDS (own row only).
  {
    const float4* __restrict__ gh =
        reinterpret_cast<const float4*>(weight + (size_t)n * N_NEUR + 128);
#pragma unroll
    for (int s2 = 0; s2 < 32; ++s2) wlds4[wrow + (s2 ^ lane_sw)] = gh[s2];
  }

  // Columns [0,128): 128 scalars resident in AGPRs (def+use class-locked).
  const float4* __restrict__ w4 =
      reinterpret_cast<const float4*>(weight + (size_t)n * N_NEUR);
  FOR32(WDECL)
  FOR32(WLOADPIN)

  const uint32_t idx = (uint32_t)(s * N_NEUR + n);

  float hist[20];
  if (t0 == 0) {
#pragma unroll
    for (int i = 0; i < 20; ++i) hist[i] = 0.0f;
  } else {
#pragma unroll
    for (int i = 0; i < 20; ++i) hist[i] = histws[i * LANES + idx];
  }

  const size_t plane = (size_t)N_SAMP * T_BINS * N_NEUR;
  float* __restrict__ out_spk = out + 0 * plane + (size_t)s * T_BINS * N_NEUR + n;
  float* __restrict__ out_cnv = out + 1 * plane + (size_t)s * T_BINS * N_NEUR + n;
  float* __restrict__ out_rte = out + 2 * plane + (size_t)s * T_BINS * N_NEUR + n;

  // MODE 0: prefetch step-t0 subkeys. MODE 1: prefetch step-t0 S-prefixes.
  uint32_t skreg = 0;
  float4 sc0, sc1;
  if constexpr (MODE == 0) {
    if (n < 2 * J_MAX) skreg = sub[(size_t)t0 * (2 * J_MAX) + n];
  } else {
    const float4* p = reinterpret_cast<const float4*>(S8 + (size_t)idx * J_PRE);
    sc0 = p[0]; sc1 = p[1];
  }

  __syncthreads();  // fb visible

  for (int t = t0; t < t1; ++t) {
    const int buf = t & 1;
    float* __restrict__ convbuf = convb + buf * N_NEUR;
    const float4* __restrict__ convbuf4 = reinterpret_cast<const float4*>(convbuf);

    float4 sn0, sn1;
    if constexpr (MODE == 0) {
      uint32_t* __restrict__ skbuf = skb + buf * 2 * J_MAX;
      if (n < 2 * J_MAX) {
        skbuf[n] = skreg;
        const int tn = (t + 1 < t1) ? t + 1 : t;
        skreg = sub[(size_t)tn * (2 * J_MAX) + n];
      }
    } else {
      // issue next step's S load early; consumed at loop bottom
      const int tn = (t + 1 < t1) ? t + 1 : t;
      const float4* p = reinterpret_cast<const float4*>(
          S8 + ((size_t)(tn - t0) * LANES + idx) * J_PRE);
      sn0 = p[0]; sn1 = p[1];
    }

    // conv: ascending w, unfused mul+add (order bit-locked)
    float conv = 0.0f;
#pragma unroll
    for (int w = 0; w < 20; ++w) {
#if CONV_FMA
      conv = __builtin_fmaf(fb[w], hist[w], conv);
#else
      conv = fadd_s(conv, fmul_s(fb[w], hist[w]));
#endif
    }
    convbuf[n] = conv;

#if RAW_BARRIER
    asm volatile("s_waitcnt lgkmcnt(0)\n\ts_barrier" ::: "memory");
#else
    __syncthreads();
#endif

    // z = sum_k conv[k]*W[n][k], fused FMA ascending k (order bit-locked)
    float zacc = 0.0f;
    ZCHUNK(0,1,2,3,4,5,6,7)
    ZCHUNK(8,9,10,11,12,13,14,15)
    ZCHUNK(16,17,18,19,20,21,22,23)
    ZCHUNK(24,25,26,27,28,29,30,31)
#pragma unroll
    for (int c2 = 0; c2 < 4; ++c2) {
      float4 wv[8], cv[8];
#pragma unroll
      for (int u = 0; u < 8; ++u) {
        const int s2 = 8 * c2 + u;
        wv[u] = wlds4[wrow + (s2 ^ lane_sw)];
        cv[u] = convbuf4[32 + s2];
      }
#pragma unroll
      for (int u = 0; u < 8; ++u) {
        zacc = __builtin_fmaf(cv[u].x, wv[u].x, zacc);
        zacc = __builtin_fmaf(cv[u].y, wv[u].y, zacc);
        zacc = __builtin_fmaf(cv[u].z, wv[u].z, zacc);
        zacc = __builtin_fmaf(cv[u].w, wv[u].w, zacc);
      }
    }
    const float zb = fadd_s(zacc, bias_n);

    // lam = 1 / (1 + exp(-z))
    const float lam = 1.0f / fadd_s(1.0f, xla_expf(-zb));
    const float neg_lam = -lam;

    int r = 0;
    if constexpr (MODE == 1) {
      // S_j strictly non-increasing -> consecutive-count == count-all.
      r = (sc0.x > neg_lam) + (sc0.y > neg_lam) + (sc0.z > neg_lam) +
          (sc0.w > neg_lam) + (sc1.x > neg_lam) + (sc1.y > neg_lam) +
          (sc1.z > neg_lam) + (sc1.w > neg_lam);
      if (sc1.w > neg_lam) {  // rare (P <= 1e-5): continue the exact chain
        float S = sc1.w;
#pragma unroll 1
        for (int j = J_PRE; j < J_MAX; ++j) {
          const uint32_t k0 = sub[(size_t)t * (2 * J_MAX) + 2 * j];
          const uint32_t k1 = sub[(size_t)t * (2 * J_MAX) + 2 * j + 1];
          uint32_t o0, o1;
          threefry2x32(k0, k1, 0u, idx, o0, o1);
#if BITS32_XOR
          const uint32_t bits = o0 ^ o1;
#else
          const uint32_t bits = o1;
#endif
          const float u = __uint_as_float((bits >> 9) | 0x3f800000u) - 1.0f;
          S = fadd_s(S, xla_logf(u));
          if (S > neg_lam) ++r; else break;
        }
      }
    } else {
      uint32_t* __restrict__ skbuf = skb + buf * 2 * J_MAX;
      float S = 0.0f;
      bool done = false;
#pragma unroll 1
      for (int jb = 0; jb < J_MAX; jb += POISSON_BATCH) {
        float L[POISSON_BATCH];
#pragma unroll
        for (int q = 0; q < POISSON_BATCH; ++q) {
          const int j = jb + q;
          uint32_t o0, o1;
          threefry2x32(skbuf[2 * j], skbuf[2 * j + 1], 0u, idx, o0, o1);
#if BITS32_XOR
          const uint32_t bits = o0 ^ o1;
#else
          const uint32_t bits = o1;
#endif
          const float u = __uint_as_float((bits >> 9) | 0x3f800000u) - 1.0f;
          L[q] = xla_logf(u);
        }
#pragma unroll
        for (int q = 0; q < POISSON_BATCH; ++q) {
          if (!done) {
            S = fadd_s(S, L[q]);
            if (S > neg_lam) ++r; else done = true;
          }
        }
        if (__all(done)) break;
      }
    }
    const float spk = (float)r;

#pragma unroll
    for (int i = 0; i < 19; ++i) hist[i] = hist[i + 1];
    hist[19] = spk;

    const size_t off = (size_t)t * N_NEUR;
#if NT_STORES
    __builtin_nontemporal_store(spk,  out_spk + off);
    __builtin_nontemporal_store(conv, out_cnv + off);
    __builtin_nontemporal_store(lam,  out_rte + off);
#else
    out_spk[off] = spk;
    out_cnv[off] = conv;
    out_rte[off] = lam;
#endif
    if constexpr (MODE == 1) { sc0 = sn0; sc1 = sn1; }
#if !RAW_BARRIER
    __syncthreads();
#endif
  }

  // Chunk handoff: persist hist for the next launch.
  if (t1 < T_BINS) {
#pragma unroll
    for (int i = 0; i < 20; ++i) histws[i * LANES + idx] = hist[i];
  }
}

extern "C" void kernel_launch(void* const* d_in, const int* in_sizes, int n_in,
                              void* d_out, int out_size, void* d_ws, size_t ws_size,
                              hipStream_t stream) {
  const float* basis  = (const float*)d_in[0];
  const float* weight = (const float*)d_in[1];
  const float* bias   = (const float*)d_in[2];
  float* out = (float*)d_out;
  char* ws = (char*)d_ws;
  uint32_t* sub = (uint32_t*)ws;
  float* histws = (float*)(ws + HIST_OFF);
  float* stbl = (float*)(ws + STBL_OFF);

  hipFuncSetAttribute(reinterpret_cast<const void*>(&poglm_main<0>),
                      hipFuncAttributeMaxDynamicSharedMemorySize, LDS_BYTES);
  hipFuncSetAttribute(reinterpret_cast<const void*>(&poglm_main<1>),
                      hipFuncAttributeMaxDynamicSharedMemorySize, LDS_BYTES);

  hipLaunchKernelGGL(poglm_subkeys, dim3((T_BINS + 255) / 256), dim3(256), 0,
                     stream, sub);

  // Pick largest T-chunk whose S-table fits the workspace.
  int chunkT = 0;
  for (int c = T_BINS; c >= 64; c >>= 1) {
    const size_t bytes = (size_t)c * LANES * J_PRE * 4;
    if (STBL_OFF + bytes <= ws_size) { chunkT = c; break; }
  }

  if (chunkT == 0) {
    // Workspace too small: inline-Poisson fallback (R8 behavior).
    hipLaunchKernelGGL((poglm_main<0>), dim3(N_SAMP), dim3(256), LDS_BYTES,
                       stream, basis, weight, bias, sub, out,
                       (const float*)nullptr, histws, 0, T_BINS);
    return;
  }

  for (int t0 = 0; t0 < T_BINS; t0 += chunkT) {
    const int t1 = t0 + chunkT;
    hipLaunchKernelGGL(poglm_stable, dim3(chunkT * (LANES / 256)), dim3(256), 0,
                       stream, sub, stbl, t0);
    hipLaunchKernelGGL((poglm_main<1>), dim3(N_SAMP), dim3(256), LDS_BYTES,
                       stream, basis, weight, bias, sub, out,
                       (const float*)stbl, histws, t0, t1);
  }
}

// Round 10
// 2169.164 us; speedup vs baseline: 2.1910x; 1.1530x over previous
//
#include <hip/hip_runtime.h>
#include <stdint.h>
#include <math.h>

// ============================================================================
// POGLM.sample — bit-exact replication of the JAX-CPU reference.
// R10: ALL 256 weights per thread in AGPRs (def+use class-locked, the
//      R7-proven pattern, now 256-wide: 256 AGPR + ~150 VGPR < 512 unified).
//      Deletes the per-lane-distinct weight LDS reads that made R9's z-phase
//      LDS-pipe-bound (~1540cy/step). LDS now only conv broadcasts + staging.
//      Poisson via precomputed S-prefix table (R9). Arithmetic identical to
//      passing R1-R9 (absmax 0.0625).
// Variant knobs:
#define THREEFRY_PARTITIONABLE 1
#define BITS32_XOR 1
#define VSL_FMA 0
#define CONV_FMA 0
#define RAW_BARRIER 1
#define POISSON_BATCH 4   // inline-path batch (MODE 0 fallback)
#define NT_STORES 1
#define J_PRE 8           // precomputed prefix depth
// ============================================================================

#define T_BINS 1024
#define N_SAMP 64
#define N_NEUR 256
#define J_MAX 32
#define LANES (N_SAMP * N_NEUR)  // 16384

// d_ws layout:
//   [0, 256KB)                sub:  [1024][32][2] u32
//   [256KB, +1.25MB)          hist: [20][16384] f32 (chunk handoff)
//   [STBL_OFF, ...)           S-table: [chunkT][16384][8] f32
#define SUB_BYTES   (T_BINS * 2 * J_MAX * 4)
#define HIST_OFF    SUB_BYTES
#define HIST_BYTES  (20 * LANES * 4)
#define STBL_OFF    (HIST_OFF + HIST_BYTES)

// --- strict (non-contractable) f32 ops ---
static __device__ __forceinline__ float fmul_s(float a, float b) {
#pragma clang fp contract(off)
  return a * b;
}
static __device__ __forceinline__ float fadd_s(float a, float b) {
#pragma clang fp contract(off)
  return a + b;
}
static __device__ __forceinline__ float fsub_s(float a, float b) {
#pragma clang fp contract(off)
  return a - b;
}

#if VSL_FMA
#define MULADD(a, b, c) __builtin_fmaf((a), (b), (c))
#else
#define MULADD(a, b, c) fadd_s(fmul_s((a), (b)), (c))
#endif

// --- Threefry-2x32, 20 rounds (exact JAX semantics) ---
static __device__ __forceinline__ uint32_t rotl(uint32_t v, uint32_t d) {
  return (v << d) | (v >> (32u - d));
}
static __device__ __forceinline__ void threefry2x32(uint32_t k0, uint32_t k1,
                                                    uint32_t x0, uint32_t x1,
                                                    uint32_t& o0, uint32_t& o1) {
  const uint32_t k2 = k0 ^ k1 ^ 0x1BD11BDAu;
  x0 += k0; x1 += k1;
#define TF_RD(r) { x0 += x1; x1 = rotl(x1, r); x1 ^= x0; }
  TF_RD(13u) TF_RD(15u) TF_RD(26u) TF_RD(6u)
  x0 += k1; x1 += k2 + 1u;
  TF_RD(17u) TF_RD(29u) TF_RD(16u) TF_RD(24u)
  x0 += k2; x1 += k0 + 2u;
  TF_RD(13u) TF_RD(15u) TF_RD(26u) TF_RD(6u)
  x0 += k0; x1 += k1 + 3u;
  TF_RD(17u) TF_RD(29u) TF_RD(16u) TF_RD(24u)
  x0 += k1; x1 += k2 + 4u;
  TF_RD(13u) TF_RD(15u) TF_RD(26u) TF_RD(6u)
  x0 += k2; x1 += k0 + 5u;
#undef TF_RD
  o0 = x0; o1 = x1;
}

// --- XLA CPU Cephes expf (GenerateVF32Exp) ---
static __device__ __forceinline__ float xla_expf(float input) {
  float x = fminf(input, 88.3762626647950f);
  x = fmaxf(x, -88.3762626647949f);
  float fx = floorf(MULADD(x, 1.44269504088896341f, 0.5f));
  float tmp = fmul_s(0.693359375f, fx);
  float z = fmul_s(-2.12194440e-4f, fx);
  x = fsub_s(x, tmp);
  x = fsub_s(x, z);
  z = fmul_s(x, x);
  float y = MULADD(x, 1.9875691500e-4f, 1.3981999507e-3f);
  y = MULADD(y, x, 8.3334519073e-3f);
  y = MULADD(y, x, 4.1665795894e-2f);
  y = MULADD(y, x, 1.6666665459e-1f);
  y = MULADD(y, x, 5.0000001201e-1f);
  y = MULADD(y, z, x);
  y = fadd_s(1.0f, y);
  int n = (int)fx;
  float p2n = __int_as_float((uint32_t)(n + 127) << 23);
  float res = fmul_s(y, p2n);
  return fmaxf(res, input);
}

// --- XLA CPU Cephes logf (GenerateVF32Log); u in {0} U [2^-23, 1) here ---
static __device__ __forceinline__ float xla_logf(float u) {
  if (u == 0.0f) return -INFINITY;
  uint32_t b = __float_as_uint(u);
  float e = (float)((int)(b >> 23) - 127) + 1.0f;
  float m = __uint_as_float((b & 0x007fffffu) | 0x3f000000u);
  if (m < 0.707106781186547524f) {
    e = fsub_s(e, 1.0f);
    m = fadd_s(m, m);
  }
  m = fsub_s(m, 1.0f);
  float z = fmul_s(m, m);
  float y = MULADD(m, 7.0376836292e-2f, -1.1514610310e-1f);
  y = MULADD(y, m, 1.1676998740e-1f);
  y = MULADD(y, m, -1.2420140846e-1f);
  y = MULADD(y, m, 1.4249322787e-1f);
  y = MULADD(y, m, -1.6668057665e-1f);
  y = MULADD(y, m, 2.0000714765e-1f);
  y = MULADD(y, m, -2.4999993993e-1f);
  y = MULADD(y, m, 3.3333331174e-1f);
  y = fmul_s(y, m);
  y = fmul_s(y, z);
  y = MULADD(e, -2.12194440e-4f, y);
  y = MULADD(z, -0.5f, y);
  m = fadd_s(m, y);
  m = MULADD(e, 0.693359375f, m);
  return m;
}

// ============================================================================
// Kernel 1: per-time-step subkey chains. sub layout: [t][j][2] u32.
// ============================================================================
__global__ void poglm_subkeys(uint32_t* __restrict__ sub) {
  int t = blockIdx.x * blockDim.x + threadIdx.x;
  if (t >= T_BINS) return;
  uint32_t kt0, kt1;
#if THREEFRY_PARTITIONABLE
  threefry2x32(0u, 1u, 0u, (uint32_t)t, kt0, kt1);
#else
  {
    uint32_t i0 = 2u * t, i1 = 2u * t + 1u, a0, a1, b0, b1;
    if (i0 < 1024u) { threefry2x32(0u, 1u, i0, i0 + 1024u, a0, a1); kt0 = a0; }
    else            { threefry2x32(0u, 1u, i0 - 1024u, i0, a0, a1); kt0 = a1; }
    if (i1 < 1024u) { threefry2x32(0u, 1u, i1, i1 + 1024u, b0, b1); kt1 = b0; }
    else            { threefry2x32(0u, 1u, i1 - 1024u, i1, b0, b1); kt1 = b1; }
  }
#endif
  uint32_t r0 = kt0, r1 = kt1;
  for (int j = 0; j < J_MAX; ++j) {
    uint32_t s0, s1, n0, n1;
#if THREEFRY_PARTITIONABLE
    threefry2x32(r0, r1, 0u, 1u, s0, s1);
    threefry2x32(r0, r1, 0u, 0u, n0, n1);
#else
    uint32_t p00, p01, p10, p11;
    threefry2x32(r0, r1, 0u, 2u, p00, p01);
    threefry2x32(r0, r1, 1u, 3u, p10, p11);
    n0 = p00; n1 = p10;
    s0 = p01; s1 = p11;
#endif
    sub[(size_t)t * (2 * J_MAX) + 2 * j + 0] = s0;
    sub[(size_t)t * (2 * J_MAX) + 2 * j + 1] = s1;
    r0 = n0; r1 = n1;
  }
}

// ============================================================================
// Kernel 1b: S-prefix table. One thread per (t, s, n); 8 draws, byte-identical
// chain S_j = fadd_s(S_{j-1}, xla_logf(u_j)). Grid fills the whole device.
// Layout: S8[((t-t0)*LANES + idx)*8 + j].
// ============================================================================
__global__ __launch_bounds__(256)
void poglm_stable(const uint32_t* __restrict__ sub, float* __restrict__ S8,
                  int t0) {
  const int g   = blockIdx.x * 256 + threadIdx.x;
  const int tt  = t0 + g / LANES;
  const int ln  = g % LANES;
  float S = 0.0f;
  float v[J_PRE];
#pragma unroll
  for (int j = 0; j < J_PRE; ++j) {
    const uint32_t k0 = sub[(size_t)tt * (2 * J_MAX) + 2 * j];
    const uint32_t k1 = sub[(size_t)tt * (2 * J_MAX) + 2 * j + 1];
    uint32_t o0, o1;
    threefry2x32(k0, k1, 0u, (uint32_t)ln, o0, o1);
#if BITS32_XOR
    const uint32_t bits = o0 ^ o1;
#else
    const uint32_t bits = o1;
#endif
    const float u = __uint_as_float((bits >> 9) | 0x3f800000u) - 1.0f;
    S = fadd_s(S, xla_logf(u));
    v[j] = S;
  }
  float4* dst = reinterpret_cast<float4*>(S8 + (size_t)g * J_PRE);
  dst[0] = make_float4(v[0], v[1], v[2], v[3]);
  dst[1] = make_float4(v[4], v[5], v[6], v[7]);
}

// ---- 64 x float4 = 256 AGPR-resident weights --------------------------------
#define FOR64(M) \
  M(0) M(1) M(2) M(3) M(4) M(5) M(6) M(7) M(8) M(9) M(10) M(11) M(12) M(13) \
  M(14) M(15) M(16) M(17) M(18) M(19) M(20) M(21) M(22) M(23) M(24) M(25)   \
  M(26) M(27) M(28) M(29) M(30) M(31) M(32) M(33) M(34) M(35) M(36) M(37)   \
  M(38) M(39) M(40) M(41) M(42) M(43) M(44) M(45) M(46) M(47) M(48) M(49)   \
  M(50) M(51) M(52) M(53) M(54) M(55) M(56) M(57) M(58) M(59) M(60) M(61)   \
  M(62) M(63)

#define WDECL(i) float wA##i, wB##i, wC##i, wD##i;

// Def: value born in AGPR class; load->write interleaved keeps VGPR pressure low.
#define WLOADPIN(i)                                                          \
  { const float4 v_ = w4[i];                                                 \
    asm volatile("v_accvgpr_write_b32 %0, %1" : "=a"(wA##i) : "v"(v_.x));    \
    asm volatile("v_accvgpr_write_b32 %0, %1" : "=a"(wB##i) : "v"(v_.y));    \
    asm volatile("v_accvgpr_write_b32 %0, %1" : "=a"(wC##i) : "v"(v_.z));    \
    asm volatile("v_accvgpr_write_b32 %0, %1" : "=a"(wD##i) : "v"(v_.w)); }

// Use: every read "a"-constrained (volatile: no hoisting 256 copies).
#define LOADCV(u, i) const float4 cv##u = convbuf4[i];
#define AFMA(u, i)                                                           \
  { float wa_, wb_, wc_, wd_;                                                \
    asm volatile("v_accvgpr_read_b32 %0, %1" : "=v"(wa_) : "a"(wA##i));      \
    asm volatile("v_accvgpr_read_b32 %0, %1" : "=v"(wb_) : "a"(wB##i));      \
    asm volatile("v_accvgpr_read_b32 %0, %1" : "=v"(wc_) : "a"(wC##i));      \
    asm volatile("v_accvgpr_read_b32 %0, %1" : "=v"(wd_) : "a"(wD##i));      \
    zacc = __builtin_fmaf(cv##u.x, wa_, zacc);                               \
    zacc = __builtin_fmaf(cv##u.y, wb_, zacc);                               \
    zacc = __builtin_fmaf(cv##u.z, wc_, zacc);                               \
    zacc = __builtin_fmaf(cv##u.w, wd_, zacc); }

#define ZCHUNK(i0,i1,i2,i3,i4,i5,i6,i7)                                      \
  { LOADCV(0,i0) LOADCV(1,i1) LOADCV(2,i2) LOADCV(3,i3)                      \
    LOADCV(4,i4) LOADCV(5,i5) LOADCV(6,i6) LOADCV(7,i7)                      \
    AFMA(0,i0) AFMA(1,i1) AFMA(2,i2) AFMA(3,i3)                              \
    AFMA(4,i4) AFMA(5,i5) AFMA(6,i6) AFMA(7,i7) }

// ============================================================================
// Kernel 2: main simulation over [t0, t1). MODE 1 = S-table Poisson (+ rare
// inline continuation); MODE 0 = inline Poisson fallback.
// ============================================================================
template <int MODE>
__global__ __launch_bounds__(256, 1)
void poglm_main(const float* __restrict__ basis, const float* __restrict__ weight,
                const float* __restrict__ bias, const uint32_t* __restrict__ sub,
                float* __restrict__ out, const float* __restrict__ S8,
                float* __restrict__ histws, int t0, int t1) {
  __shared__ alignas(16) float convb[2][N_NEUR];
  __shared__ uint32_t skb[2][2 * J_MAX];
  __shared__ float fb[20];

  const int s = blockIdx.x;
  const int n = threadIdx.x;

  if (n < 20) fb[n] = basis[19 - n];
  const float bias_n = bias[n];

  // Whole weight row (256 scalars) resident in AGPRs (def+use class-locked).
  const float4* __restrict__ w4 =
      reinterpret_cast<const float4*>(weight + (size_t)n * N_NEUR);
  FOR64(WDECL)
  FOR64(WLOADPIN)

  const uint32_t idx = (uint32_t)(s * N_NEUR + n);

  float hist[20];
  if (t0 == 0) {
#pragma unroll
    for (int i = 0; i < 20; ++i) hist[i] = 0.0f;
  } else {
#pragma unroll
    for (int i = 0; i < 20; ++i) hist[i] = histws[i * LANES + idx];
  }

  const size_t plane = (size_t)N_SAMP * T_BINS * N_NEUR;
  float* __restrict__ out_spk = out + 0 * plane + (size_t)s * T_BINS * N_NEUR + n;
  float* __restrict__ out_cnv = out + 1 * plane + (size_t)s * T_BINS * N_NEUR + n;
  float* __restrict__ out_rte = out + 2 * plane + (size_t)s * T_BINS * N_NEUR + n;

  uint32_t skreg = 0;
  float4 sc0, sc1;
  if constexpr (MODE == 0) {
    if (n < 2 * J_MAX) skreg = sub[(size_t)t0 * (2 * J_MAX) + n];
  } else {
    const float4* p = reinterpret_cast<const float4*>(S8 + (size_t)idx * J_PRE);
    sc0 = p[0]; sc1 = p[1];
  }

  __syncthreads();  // fb visible

  for (int t = t0; t < t1; ++t) {
    const int buf = t & 1;
    float* __restrict__ convbuf = convb[buf];
    const float4* __restrict__ convbuf4 = reinterpret_cast<const float4*>(convbuf);

    float4 sn0, sn1;
    if constexpr (MODE == 0) {
      uint32_t* __restrict__ skbuf = skb[buf];
      if (n < 2 * J_MAX) {
        skbuf[n] = skreg;
        const int tn = (t + 1 < t1) ? t + 1 : t;
        skreg = sub[(size_t)tn * (2 * J_MAX) + n];
      }
    } else {
      const int tn = (t + 1 < t1) ? t + 1 : t;
      const float4* p = reinterpret_cast<const float4*>(
          S8 + ((size_t)(tn - t0) * LANES + idx) * J_PRE);
      sn0 = p[0]; sn1 = p[1];
    }

    // conv: ascending w, unfused mul+add (order bit-locked)
    float conv = 0.0f;
#pragma unroll
    for (int w = 0; w < 20; ++w) {
#if CONV_FMA
      conv = __builtin_fmaf(fb[w], hist[w], conv);
#else
      conv = fadd_s(conv, fmul_s(fb[w], hist[w]));
#endif
    }
    convbuf[n] = conv;

#if RAW_BARRIER
    asm volatile("s_waitcnt lgkmcnt(0)\n\ts_barrier" ::: "memory");
#else
    __syncthreads();
#endif

    // z = sum_k conv[k]*W[n][k], fused FMA ascending k (order bit-locked),
    // all weights from AGPRs; conv via wave-uniform LDS broadcasts.
    float zacc = 0.0f;
    ZCHUNK(0,1,2,3,4,5,6,7)
    ZCHUNK(8,9,10,11,12,13,14,15)
    ZCHUNK(16,17,18,19,20,21,22,23)
    ZCHUNK(24,25,26,27,28,29,30,31)
    ZCHUNK(32,33,34,35,36,37,38,39)
    ZCHUNK(40,41,42,43,44,45,46,47)
    ZCHUNK(48,49,50,51,52,53,54,55)
    ZCHUNK(56,57,58,59,60,61,62,63)
    const float zb = fadd_s(zacc, bias_n);

    // lam = 1 / (1 + exp(-z))
    const float lam = 1.0f / fadd_s(1.0f, xla_expf(-zb));
    const float neg_lam = -lam;

    int r = 0;
    if constexpr (MODE == 1) {
      // S_j strictly non-increasing -> consecutive-count == count-all.
      r = (sc0.x > neg_lam) + (sc0.y > neg_lam) + (sc0.z > neg_lam) +
          (sc0.w > neg_lam) + (sc1.x > neg_lam) + (sc1.y > neg_lam) +
          (sc1.z > neg_lam) + (sc1.w > neg_lam);
      if (sc1.w > neg_lam) {  // rare (P <= 1e-5): continue the exact chain
        float S = sc1.w;
#pragma unroll 1
        for (int j = J_PRE; j < J_MAX; ++j) {
          const uint32_t k0 = sub[(size_t)t * (2 * J_MAX) + 2 * j];
          const uint32_t k1 = sub[(size_t)t * (2 * J_MAX) + 2 * j + 1];
          uint32_t o0, o1;
          threefry2x32(k0, k1, 0u, idx, o0, o1);
#if BITS32_XOR
          const uint32_t bits = o0 ^ o1;
#else
          const uint32_t bits = o1;
#endif
          const float u = __uint_as_float((bits >> 9) | 0x3f800000u) - 1.0f;
          S = fadd_s(S, xla_logf(u));
          if (S > neg_lam) ++r; else break;
        }
      }
    } else {
      uint32_t* __restrict__ skbuf = skb[buf];
      float S = 0.0f;
      bool done = false;
#pragma unroll 1
      for (int jb = 0; jb < J_MAX; jb += POISSON_BATCH) {
        float L[POISSON_BATCH];
#pragma unroll
        for (int q = 0; q < POISSON_BATCH; ++q) {
          const int j = jb + q;
          uint32_t o0, o1;
          threefry2x32(skbuf[2 * j], skbuf[2 * j + 1], 0u, idx, o0, o1);
#if BITS32_XOR
          const uint32_t bits = o0 ^ o1;
#else
          const uint32_t bits = o1;
#endif
          const float u = __uint_as_float((bits >> 9) | 0x3f800000u) - 1.0f;
          L[q] = xla_logf(u);
        }
#pragma unroll
        for (int q = 0; q < POISSON_BATCH; ++q) {
          if (!done) {
            S = fadd_s(S, L[q]);
            if (S > neg_lam) ++r; else done = true;
          }
        }
        if (__all(done)) break;
      }
    }
    const float spk = (float)r;

#pragma unroll
    for (int i = 0; i < 19; ++i) hist[i] = hist[i + 1];
    hist[19] = spk;

    const size_t off = (size_t)t * N_NEUR;
#if NT_STORES
    __builtin_nontemporal_store(spk,  out_spk + off);
    __builtin_nontemporal_store(conv, out_cnv + off);
    __builtin_nontemporal_store(lam,  out_rte + off);
#else
    out_spk[off] = spk;
    out_cnv[off] = conv;
    out_rte[off] = lam;
#endif
    if constexpr (MODE == 1) { sc0 = sn0; sc1 = sn1; }
#if !RAW_BARRIER
    __syncthreads();
#endif
  }

  // Chunk handoff: persist hist for the next launch.
  if (t1 < T_BINS) {
#pragma unroll
    for (int i = 0; i < 20; ++i) histws[i * LANES + idx] = hist[i];
  }
}

extern "C" void kernel_launch(void* const* d_in, const int* in_sizes, int n_in,
                              void* d_out, int out_size, void* d_ws, size_t ws_size,
                              hipStream_t stream) {
  const float* basis  = (const float*)d_in[0];
  const float* weight = (const float*)d_in[1];
  const float* bias   = (const float*)d_in[2];
  float* out = (float*)d_out;
  char* ws = (char*)d_ws;
  uint32_t* sub = (uint32_t*)ws;
  float* histws = (float*)(ws + HIST_OFF);
  float* stbl = (float*)(ws + STBL_OFF);

  hipLaunchKernelGGL(poglm_subkeys, dim3((T_BINS + 255) / 256), dim3(256), 0,
                     stream, sub);

  // Pick largest T-chunk whose S-table fits the workspace.
  int chunkT = 0;
  for (int c = T_BINS; c >= 64; c >>= 1) {
    const size_t bytes = (size_t)c * LANES * J_PRE * 4;
    if (STBL_OFF + bytes <= ws_size) { chunkT = c; break; }
  }

  if (chunkT == 0) {
    hipLaunchKernelGGL((poglm_main<0>), dim3(N_SAMP), dim3(256), 0,
                       stream, basis, weight, bias, sub, out,
                       (const float*)nullptr, histws, 0, T_BINS);
    return;
  }

  for (int t0 = 0; t0 < T_BINS; t0 += chunkT) {
    const int t1 = t0 + chunkT;
    hipLaunchKernelGGL(poglm_stable, dim3(chunkT * (LANES / 256)), dim3(256), 0,
                       stream, sub, stbl, t0);
    hipLaunchKernelGGL((poglm_main<1>), dim3(N_SAMP), dim3(256), 0,
                       stream, basis, weight, bias, sub, out,
                       (const float*)stbl, histws, t0, t1);
  }
}